// Round 16
// baseline (751.547 us; speedup 1.0000x reference)
//
#include <hip/hip_runtime.h>
#include <math.h>

#define NN 100000
#define EE 1600000
#define SCB 98    // ceil(NN/1024)
#define GB1 1564  // ceil(NN/128)*2 col-halves
#define FB 3125   // ceil(EE/512)

typedef __attribute__((ext_vector_type(8))) short bf16x8;
typedef __attribute__((ext_vector_type(4))) short bf16x4;
typedef __attribute__((ext_vector_type(4))) float f32x4;

__device__ __forceinline__ unsigned short f2bf(float x){
  union { float f; unsigned u; } v; v.f = x;
  unsigned r = v.u + 0x7FFFu + ((v.u >> 16) & 1u);
  return (unsigned short)(r >> 16);
}
__device__ __forceinline__ float bf2f(unsigned short h){
  union { unsigned u; float f; } v; v.u = ((unsigned)h) << 16; return v.f;
}
__device__ __forceinline__ float sigm(float x){ return 1.0f/(1.0f+__expf(-x)); }

// light barrier: ds-ops drained, global loads stay in flight (T3/T4; guide §5)
__device__ __forceinline__ void barrier_lds_only(){
  asm volatile("s_waitcnt lgkmcnt(0)" ::: "memory");
  __builtin_amdgcn_s_barrier();
  __builtin_amdgcn_sched_barrier(0);
}

// ---------------- degree + weight convert (merged) ----------------
// W1T layout for k_g1fill: [khalf(2)][colhalf(2)][col(64)][slot(64)][8],
// slot pre-XOR-swizzled: logical kslot = slot ^ (col&7), k = kh*512 + kslot*8 + e.
// Others: chunked [chunk(64k)][col][k-in-chunk]; W3c: [col(16)][k(128)]
__global__ __launch_bounds__(256) void k_deg_wcvt(const int* __restrict__ src, const int* __restrict__ dst,
                      int* __restrict__ dout, int* __restrict__ din,
                      const float* __restrict__ W1, const float* __restrict__ W2,
                      const float* __restrict__ Wdo, const float* __restrict__ W3,
                      unsigned short* __restrict__ W1T, unsigned short* __restrict__ W2T,
                      unsigned short* __restrict__ WdoB, unsigned short* __restrict__ W3c){
  int b = blockIdx.x;
  if (b < EE/256){
    int e = b*256 + threadIdx.x;
    atomicAdd(&dout[src[e]],1); atomicAdd(&din[dst[e]],1);
  } else {
    int i = (b - EE/256)*256 + threadIdx.x;
    if (i < 131072){
      int kh = i>>16, r = i&65535;
      int chh = r>>15, r2 = r&32767;
      int colh = r2>>9, s = (r2>>3)&63, e2 = i&7;
      int kslot = s ^ (colh&7);
      int k = kh*512 + kslot*8 + e2;
      W1T[i] = f2bf(W1[(size_t)k*128 + chh*64 + colh]);
    } else if (i < 147456){
      int j = i-131072;
      int c = j>>13, r = j&8191, col = r>>6, k = c*64 + (r&63);
      W2T[j] = f2bf(W2[(size_t)k*128 + col]);
    } else if (i < 163840){
      int j = i-147456;
      int c = j>>13, r = j&8191, col = r>>6, k = c*64 + (r&63);
      WdoB[j] = f2bf(Wdo[(size_t)col*128 + k]);   // B = Wdo^T
    } else if (i < 165888){
      int j = i-163840;
      int col = j>>7, k = j&127;
      W3c[j] = f2bf(W3[(size_t)k*16 + col]);
    }
  }
}

// ---------------- parallel scan ----------------
__global__ __launch_bounds__(1024) void k_scan1(const int* __restrict__ din, int* __restrict__ chunk,
                        int* __restrict__ bsum){
  __shared__ int wsum[16];
  int t = threadIdx.x, lane = t & 63, w = t >> 6;
  int i = blockIdx.x*1024 + t;
  int v = (i < NN) ? din[i] : 0;
  int x = v;
  #pragma unroll
  for (int off=1; off<64; off<<=1){
    int y = __shfl_up(x, off);
    if (lane>=off) x += y;
  }
  if (lane==63) wsum[w] = x;
  __syncthreads();
  int pre = 0;
  #pragma unroll
  for (int j=0;j<16;j++) if (j<w) pre += wsum[j];
  int incl = x + pre;
  if (i < NN) chunk[i] = incl;
  if (t == 1023) bsum[blockIdx.x] = incl;
}

__global__ __launch_bounds__(128) void k_scan2(const int* __restrict__ bsum, int* __restrict__ bpre,
                       int* __restrict__ row_ptr){
  __shared__ int w0tot;
  int t = threadIdx.x, lane = t & 63, w = t >> 6;
  int v = (t < SCB) ? bsum[t] : 0;
  int x = v;
  #pragma unroll
  for (int off=1; off<64; off<<=1){
    int y = __shfl_up(x, off);
    if (lane>=off) x += y;
  }
  if (w==0 && lane==63) w0tot = x;
  __syncthreads();
  int incl = x + (w ? w0tot : 0);
  if (t < SCB) bpre[t] = incl - v;
  if (t == 0) row_ptr[0] = 0;
}

__global__ __launch_bounds__(256) void k_scan3(const int* __restrict__ din, const int* __restrict__ chunk,
                       const int* __restrict__ bpre, const int* __restrict__ dout,
                       const int* __restrict__ perm,
                       int* __restrict__ row_ptr, int* __restrict__ cursor,
                       float* __restrict__ ns, float* __restrict__ nd, int* __restrict__ inv){
  int i = blockIdx.x*256 + threadIdx.x;
  if (i < NN){
    int d = din[i];
    int val = chunk[i] + bpre[i>>10];
    row_ptr[i+1] = val;
    cursor[i] = val - d;
    ns[i] = rsqrtf((float)max(dout[i],1));
    nd[i] = rsqrtf((float)max(d,1));
    inv[perm[i]] = i;
  }
}

// ---------------- GC1 GEMM (barrier-free K-loop) fused with CSR fill ----------------
// blocks [0, GB1): block b computes rows (b>>1)*128 x cols (b&1)*64 of t=bf16(x@W1).
// B-slice staged per K-half (64KB LDS, 2 blocks/CU); A global->reg->MFMA per lane,
// 2-chunk rotating prefetch; only 3 barriers per block. blocks [GB1,..): CSR fill.
__global__ __launch_bounds__(512,2) void k_g1fill(
    const float* __restrict__ A, const unsigned short* __restrict__ Wc,
    unsigned short* __restrict__ tz,
    const int* __restrict__ src, const int* __restrict__ dst,
    int* __restrict__ cursor, int* __restrict__ col)
{
  __shared__ __align__(16) unsigned short Bs[64*512];   // 64 KB
  if (blockIdx.x >= GB1){
    int e = (blockIdx.x - GB1)*512 + threadIdx.x;
    if (e < EE){
      int pos = atomicAdd(&cursor[dst[e]],1);
      col[pos] = src[e];
    }
    return;
  }
  int t = threadIdx.x, wave = t>>6, lane = t&63;
  int rows0 = (blockIdx.x>>1)*128;
  int ch = blockIdx.x & 1;

  int arow = min(rows0 + wave*16 + (lane&15), NN-1);
  int kof = (lane>>4)*8;
  const float* ap = A + (size_t)arow*1024 + kof;
  int c = lane & 15;
  int slot0 = lane>>4;

  f32x4 acc[4] = {};
  float4 P0[4], P1[4];

#define LD(P, CC) { \
  P[0] = *(const float4*)(ap + (CC)*64); \
  P[1] = *(const float4*)(ap + (CC)*64 + 4); \
  P[2] = *(const float4*)(ap + (CC)*64 + 32); \
  P[3] = *(const float4*)(ap + (CC)*64 + 36); }

#define CHUNK(CC, P) { \
  bf16x8 af0, af1; \
  { float v0[8] = {P[0].x,P[0].y,P[0].z,P[0].w,P[1].x,P[1].y,P[1].z,P[1].w}; \
    float v1[8] = {P[2].x,P[2].y,P[2].z,P[2].w,P[3].x,P[3].y,P[3].z,P[3].w}; \
    _Pragma("unroll") \
    for (int q=0;q<8;q++){ af0[q] = (short)f2bf(v0[q]); af1[q] = (short)f2bf(v1[q]); } } \
  if ((CC)+2 < 16) LD(P, (CC)+2); \
  { int kb = ((CC)&7)*8; \
    _Pragma("unroll") \
    for (int j=0;j<4;j++){ \
      int cj = j*16 + c; \
      int s0 = (kb + slot0) ^ (cj&7); \
      bf16x8 b = *(const bf16x8*)&Bs[cj*512 + (s0<<3)]; \
      acc[j] = __builtin_amdgcn_mfma_f32_16x16x32_bf16(af0, b, acc[j], 0, 0, 0); \
    } \
    _Pragma("unroll") \
    for (int j=0;j<4;j++){ \
      int cj = j*16 + c; \
      int s1 = (kb + 4 + slot0) ^ (cj&7); \
      bf16x8 b = *(const bf16x8*)&Bs[cj*512 + (s1<<3)]; \
      acc[j] = __builtin_amdgcn_mfma_f32_16x16x32_bf16(af1, b, acc[j], 0, 0, 0); \
    } } }

  // stage B for K-half 0 (linear copy, layout pre-swizzled)
  {
    const unsigned short* wsrc = Wc + (size_t)ch*32768;
    #pragma unroll
    for (int p=0;p<8;p++)
      *(bf16x8*)&Bs[p*4096 + t*8] = *(const bf16x8*)&wsrc[p*4096 + t*8];
  }
  LD(P0, 0); LD(P1, 1);
  __syncthreads();

  CHUNK(0,P0)  CHUNK(1,P1)  CHUNK(2,P0)  CHUNK(3,P1)
  CHUNK(4,P0)  CHUNK(5,P1)  CHUNK(6,P0)  CHUNK(7,P1)

  // restage B for K-half 1
  __syncthreads();
  {
    const unsigned short* wsrc = Wc + 65536 + (size_t)ch*32768;
    #pragma unroll
    for (int p=0;p<8;p++)
      *(bf16x8*)&Bs[p*4096 + t*8] = *(const bf16x8*)&wsrc[p*4096 + t*8];
  }
  barrier_lds_only();

  CHUNK(8,P0)  CHUNK(9,P1)  CHUNK(10,P0) CHUNK(11,P1)
  CHUNK(12,P0) CHUNK(13,P1) CHUNK(14,P0) CHUNK(15,P1)

#undef LD
#undef CHUNK

  // epilogue: coalesced write of this block's 64-col slice
  int rbase = rows0 + wave*16 + (lane>>4)*4;
  #pragma unroll
  for (int j=0;j<4;j++){
    int colx = ch*64 + j*16 + c;
    #pragma unroll
    for (int r=0;r<4;r++){
      int row = rbase + r;
      if (row < NN) tz[(size_t)row*128 + colx] = f2bf(acc[j][r]);
    }
  }
}

// ---------------- GC1 aggregation from t/perm/ns (both encodes) ----------------
__global__ __launch_bounds__(256) void k_agg1(
  const unsigned short* __restrict__ tz, const int* __restrict__ perm,
  const float* __restrict__ ns,
  const int* __restrict__ row_ptr, const int* __restrict__ col,
  const float* __restrict__ nd, const float* __restrict__ bias,
  unsigned short* __restrict__ ob)
{
  int wave = threadIdx.x>>6, lane = threadIdx.x&63;
  int row = blockIdx.x*4 + wave;
  if (row >= NN) return;
  int s = row_ptr[row], e = row_ptr[row+1];
  int es = lane>>5;
  int half = (lane>>4)&1;
  int c8 = (lane&15)*8;
  float acc[8] = {};
  bf16x8 zer = {};
  int i = s + es;

#define FETCH1(IDX, U, F) { \
  if ((IDX) < e){ \
    int sc = col[(IDX)]; \
    int rr = half ? perm[sc] : sc; \
    F = ns[sc]; \
    U = *(const bf16x8*)(tz + (size_t)rr*128 + c8); \
  } else { F = 0.0f; U = zer; } }

  bf16x8 u0, u1, u2, u3;
  float f0, f1, f2, f3;
  FETCH1(i,   u0, f0);
  FETCH1(i+2, u1, f1);
  FETCH1(i+4, u2, f2);
  FETCH1(i+6, u3, f3);
  while (i < e){
    bf16x8 w0, w1; float g0, g1;
    FETCH1(i+8,  w0, g0);
    FETCH1(i+10, w1, g1);
    #pragma unroll
    for (int j=0;j<8;j++)
      acc[j] += bf2f((unsigned short)u0[j])*f0 + bf2f((unsigned short)u1[j])*f1;
    u0=u2; f0=f2; u1=u3; f1=f3;
    u2=w0; f2=g0; u3=w1; f3=g1;
    i += 4;
  }
#undef FETCH1
  #pragma unroll
  for (int j=0;j<8;j++) acc[j] += __shfl_down(acc[j], 32);
  if (lane < 32){
    float ndr = nd[row];
    size_t oof = half ? (size_t)(NN+row)*128 + c8 : (size_t)row*128 + c8;
    bf16x8 wv;
    #pragma unroll
    for (int j=0;j<8;j++) wv[j] = (short)f2bf(acc[j]*ndr + bias[c8+j]);
    *(bf16x8*)(ob + oof) = wv;
  }
}

// ---------------- A-fragment holder (bf16 direct) ----------------
struct ARU { bf16x8 a; };
__device__ __forceinline__ void aload(ARU& r, const unsigned short* p){
  r.a = *(const bf16x8*)p;
}
template<int IM>
__device__ __forceinline__ bf16x8 aconv(const ARU& r, float rs){
  if constexpr (IM==0) return r.a;
  else {
    bf16x8 o;
    #pragma unroll
    for (int i=0;i<8;i++){
      float v = sigm(fmaxf(bf2f((unsigned short)r.a[i]),0.0f)*rs);
      o[i] = (short)f2bf(v);
    }
    return o;
  }
}
__device__ __forceinline__ bf16x8 araw(const ARU& r){ return r.a; }

// ---------------- small-K MFMA GEMM (bf16 A direct) ----------------
template<int KDIM, int IN_MODE, int OUT_MODE>
__global__ __launch_bounds__(256,2) void k_gemmA(
    const unsigned short* __restrict__ A, const unsigned short* __restrict__ Wc,
    unsigned short* __restrict__ out0,
    const float* __restrict__ scale,
    const float* __restrict__ rn, int nrows,
    float* __restrict__ ro, float* __restrict__ roa,
    const unsigned short* __restrict__ W3c, const float* __restrict__ ns2,
    unsigned short* __restrict__ th)
{
  constexpr int NC = KDIM/64;
  __shared__ __align__(16) unsigned short Bs[2*128*64];
  __shared__ __align__(16) unsigned short W3s[OUT_MODE==3 ? 16*128 : 16];
  int t = threadIdx.x, wave = t>>6, lane = t&63;
  int row0 = blockIdx.x*64;
  int arow = row0 + wave*16 + (lane&15);
  int kof = (lane>>4)*8;
  int arow_c = min(arow, nrows-1);
  const unsigned short* ap = A + (size_t)arow_c*KDIM + kof;
  float rscale = 1.0f;
  if constexpr (IN_MODE==1) rscale = rn[arow_c];

  int scol = t>>3;
  int sw = ((t&7) ^ (scol&7))<<3;

  unsigned short* b0 = &Bs[0];
  unsigned short* b1 = &Bs[128*64];
  const unsigned short* bcur = b0; unsigned short* bnxt = b1;

  f32x4 acc[8] = {};
  f32x4 acc2 = {};
  ARU A0a{},A0b{},A1a{},A1b{},A2a{},A2b{};
  bf16x8 w0{},w1{},w2{},w3{};

  {
    const unsigned short* gp = Wc + (size_t)t*8;
    bf16x8 t0 = *(const bf16x8*)(gp);
    bf16x8 t1 = *(const bf16x8*)(gp+2048);
    bf16x8 t2 = *(const bf16x8*)(gp+4096);
    bf16x8 t3 = *(const bf16x8*)(gp+6144);
    *(bf16x8*)&b0[(0*32+scol)*64 + sw] = t0;
    *(bf16x8*)&b0[(1*32+scol)*64 + sw] = t1;
    *(bf16x8*)&b0[(2*32+scol)*64 + sw] = t2;
    *(bf16x8*)&b0[(3*32+scol)*64 + sw] = t3;
  }
  if constexpr (OUT_MODE==3){
    int wc = t>>4, wsl = t&15;
    bf16x8 v = *(const bf16x8*)(W3c + wc*128 + wsl*8);
    *(bf16x8*)&W3s[wc*128 + ((wsl ^ (wc&7))<<3)] = v;
  }
  aload(A0a, ap); aload(A0b, ap+32);
  if (NC>1){
    const unsigned short* gp = Wc + 8192 + (size_t)t*8;
    w0 = *(const bf16x8*)(gp);
    w1 = *(const bf16x8*)(gp+2048);
    w2 = *(const bf16x8*)(gp+4096);
    w3 = *(const bf16x8*)(gp+6144);
    aload(A1a, ap+64); aload(A1b, ap+96);
  }
  __syncthreads();

  int slot0 = lane>>4;
  int c = lane & 15;
  #pragma unroll
  for (int cc=0; cc<NC; ++cc){
    if (cc+2 < NC){
      aload(A2a, ap + (cc+2)*64);
      aload(A2b, ap + (cc+2)*64 + 32);
    }
    {
      bf16x8 af = aconv<IN_MODE>(A0a, rscale);
      #pragma unroll
      for (int j=0;j<8;j++){
        int cj = j*16 + c;
        bf16x8 b = *(const bf16x8*)&bcur[cj*64 + ((slot0 ^ (cj&7))<<3)];
        acc[j] = __builtin_amdgcn_mfma_f32_16x16x32_bf16(af, b, acc[j], 0, 0, 0);
      }
      if constexpr (OUT_MODE==3){
        int sl = cc*8 + slot0;
        bf16x8 b = *(const bf16x8*)&W3s[c*128 + ((sl ^ (c&7))<<3)];
        acc2 = __builtin_amdgcn_mfma_f32_16x16x32_bf16(araw(A0a), b, acc2, 0, 0, 0);
      }
    }
    {
      bf16x8 af = aconv<IN_MODE>(A0b, rscale);
      #pragma unroll
      for (int j=0;j<8;j++){
        int cj = j*16 + c;
        bf16x8 b = *(const bf16x8*)&bcur[cj*64 + (((slot0+4) ^ (cj&7))<<3)];
        acc[j] = __builtin_amdgcn_mfma_f32_16x16x32_bf16(af, b, acc[j], 0, 0, 0);
      }
      if constexpr (OUT_MODE==3){
        int sl = cc*8 + 4 + slot0;
        bf16x8 b = *(const bf16x8*)&W3s[c*128 + ((sl ^ (c&7))<<3)];
        acc2 = __builtin_amdgcn_mfma_f32_16x16x32_bf16(araw(A0b), b, acc2, 0, 0, 0);
      }
    }
    if (cc+1 < NC){
      *(bf16x8*)&bnxt[(0*32+scol)*64 + sw] = w0;
      *(bf16x8*)&bnxt[(1*32+scol)*64 + sw] = w1;
      *(bf16x8*)&bnxt[(2*32+scol)*64 + sw] = w2;
      *(bf16x8*)&bnxt[(3*32+scol)*64 + sw] = w3;
      barrier_lds_only();
      const unsigned short* tmp = bcur; bcur = bnxt; bnxt = (unsigned short*)tmp;
      if (cc+2 < NC){
        const unsigned short* gp = Wc + (size_t)(cc+2)*8192 + (size_t)t*8;
        w0 = *(const bf16x8*)(gp);
        w1 = *(const bf16x8*)(gp+2048);
        w2 = *(const bf16x8*)(gp+4096);
        w3 = *(const bf16x8*)(gp+6144);
      }
    }
    A0a=A1a; A0b=A1b; A1a=A2a; A1b=A2b;
  }

  if constexpr (OUT_MODE==3){
    #pragma unroll
    for (int r=0;r<4;r++){
      int row = row0 + wave*16 + (lane>>4)*4 + r;
      int sidx = row>=NN ? row-NN : row;
      float v = acc2[r]*ns2[sidx];
      size_t tof = row<NN ? (size_t)row*32 + c : (size_t)(row-NN)*32 + 16 + c;
      th[tof] = f2bf(v);
    }
    __syncthreads();
    unsigned short* Os = &Bs[0];
    unsigned short* Oo = &Bs[8192];
    for (int p=t; p<2048; p+=256){
      int r = (p>>4)&63, seg = p&15;
      int row = row0 + r;
      int srcrow = (p<1024) ? row : (row<NN ? row+NN : row-NN);
      unsigned short* dst = (p<1024) ? Os : Oo;
      *(bf16x8*)&dst[r*128 + ((seg ^ (r&7))<<3)] = *(const bf16x8*)&A[(size_t)srcrow*128 + seg*8];
    }
    __syncthreads();
    float bb = scale[0];
    #pragma unroll
    for (int r=0;r<4;r++){
      int lr = wave*16 + (lane>>4)*4 + r;
      float dsame=0.f, doth=0.f;
      #pragma unroll
      for (int j=0;j<8;j++){
        float v = acc[j][r];
        int colj = j*16 + c;
        int idx = lr*128 + (((colj>>3) ^ (lr&7))<<3) + (colj&7);
        dsame += fmaxf(bf2f(Os[idx]),0.f)*v;
        doth  += fmaxf(bf2f(Oo[idx]),0.f)*v;
      }
      #pragma unroll
      for (int off=1; off<16; off<<=1){
        dsame += __shfl_xor(dsame, off);
        doth  += __shfl_xor(doth, off);
      }
      if (c==0){
        int row = row0 + lr;
        if (row < NN){
          ro[(size_t)row*2+0] = dsame + bb;
          ro[(size_t)row*2+1] = doth + bb;
        } else {
          int m = row - NN;
          roa[(size_t)m*2+0] = dsame + bb;
          roa[(size_t)m*2+1] = doth + bb;
        }
      }
    }
  } else {
    int rbase = row0 + wave*16 + (lane>>4)*4;
    #pragma unroll
    for (int j=0;j<8;j++){
      int colx = j*16 + c;
      #pragma unroll
      for (int r=0;r<4;r++){
        int row = rbase + r;
        if (row < nrows){
          float v = acc[j][r];
          int sidx = row >= NN ? row - NN : row;
          size_t zof = row < NN ? (size_t)row*256 + colx : (size_t)(row-NN)*256 + 128 + colx;
          out0[zof] = f2bf(v * scale[sidx]);
        }
      }
    }
  }
}

// ---------------- CSR aggregation (GC2, residual), interleaved z[N][2][128] ----------------
__global__ __launch_bounds__(256) void k_agg128(
  const unsigned short* __restrict__ z,
  const int* __restrict__ row_ptr, const int* __restrict__ col,
  const float* __restrict__ nd, const float* __restrict__ bias,
  unsigned short* __restrict__ ob, float* __restrict__ rn)
{
  int wave = threadIdx.x>>6, lane = threadIdx.x&63;
  int row = blockIdx.x*4 + wave;
  if (row >= NN) return;
  int s = row_ptr[row], e = row_ptr[row+1];
  int es = lane>>5;
  int half = (lane>>4)&1;
  int c8 = (lane&15)*8;
  size_t lof = (size_t)half*128 + c8;
  float acc[8] = {};
  int i = s + es;
  int c0 = (i   < e) ? col[i]   : -1;
  int c1 = (i+2 < e) ? col[i+2] : -1;
  int c2 = (i+4 < e) ? col[i+4] : -1;
  int c3 = (i+6 < e) ? col[i+6] : -1;
  bf16x8 u0 = {}, u1 = {}, u2 = {}, u3 = {};
  if (c0 >= 0) u0 = *(const bf16x8*)(z + (size_t)c0*256 + lof);
  if (c1 >= 0) u1 = *(const bf16x8*)(z + (size_t)c1*256 + lof);
  if (c2 >= 0) u2 = *(const bf16x8*)(z + (size_t)c2*256 + lof);
  if (c3 >= 0) u3 = *(const bf16x8*)(z + (size_t)c3*256 + lof);
  while (c0 >= 0){
    int n0 = (i+8  < e) ? col[i+8]  : -1;
    int n1 = (i+10 < e) ? col[i+10] : -1;
    bf16x8 w0 = {}, w1 = {};
    if (n0 >= 0) w0 = *(const bf16x8*)(z + (size_t)n0*256 + lof);
    if (n1 >= 0) w1 = *(const bf16x8*)(z + (size_t)n1*256 + lof);
    #pragma unroll
    for (int j=0;j<8;j++) acc[j] += bf2f((unsigned short)u0[j]) + bf2f((unsigned short)u1[j]);
    c0 = c2; c1 = c3; u0 = u2; u1 = u3;
    c2 = n0; c3 = n1; u2 = w0; u3 = w1;
    i += 4;
  }
  #pragma unroll
  for (int j=0;j<8;j++) acc[j] += __shfl_down(acc[j], 32);
  if (lane < 32){
    float ndr = nd[row];
    size_t oof = half ? (size_t)(NN+row)*128 + c8 : (size_t)row*128 + c8;
    float ra[8];
    #pragma unroll
    for (int j=0;j<8;j++) ra[j] = acc[j]*ndr + bias[c8+j];
    {
      bf16x8 pv = *(const bf16x8*)(ob + oof);
      #pragma unroll
      for (int j=0;j<8;j++) ra[j] += bf2f((unsigned short)pv[j]);
    }
    bf16x8 wv;
    #pragma unroll
    for (int j=0;j<8;j++) wv[j] = (short)f2bf(ra[j]);
    *(bf16x8*)(ob + oof) = wv;
    {
      float sa = 0.f;
      #pragma unroll
      for (int j=0;j<8;j++){ float x1 = fmaxf(ra[j],0.f); sa += x1*x1; }
      sa += __shfl_down(sa, 8);
      sa += __shfl_down(sa, 4);
      sa += __shfl_down(sa, 2);
      sa += __shfl_down(sa, 1);
      if ((lane&15)==0) rn[half ? NN+row : row] = 1.0f/fmaxf(sqrtf(sa),1e-12f);
    }
  }
}

// ---------------- width-16 aggregation (GC3) + fused ret_h ----------------
__global__ __launch_bounds__(256) void k_agg16(
  const unsigned short* __restrict__ th,
  const int* __restrict__ row_ptr, const int* __restrict__ col,
  const float* __restrict__ nd, const float* __restrict__ b3,
  const float* __restrict__ Wdh, const float* __restrict__ bdh,
  float* __restrict__ hout, float* __restrict__ rh, float* __restrict__ rha)
{
  __shared__ float Ws[256];
  __shared__ float hbuf[4][32];
  __shared__ float gbuf[4][32];
  int t = threadIdx.x;
  Ws[t] = Wdh[t];
  __syncthreads();
  int wave = t>>6, lane = t&63;
  int row = blockIdx.x*4 + wave;
  if (row >= NN) return;
  int s = row_ptr[row], e = row_ptr[row+1];
  int es = lane>>3, l8 = lane&7;
  float a4[4] = {};
  int i = s + es;
  int c0 = (i   <e)? col[i]    : -1;
  int c1 = (i+8 <e)? col[i+8]  : -1;
  int c2 = (i+16<e)? col[i+16] : -1;
  int c3 = (i+24<e)? col[i+24] : -1;
  bf16x4 u0 = {}, u1 = {}, u2 = {}, u3 = {};
  if (c0 >= 0) u0 = *(const bf16x4*)(th + (size_t)c0*32 + l8*4);
  if (c1 >= 0) u1 = *(const bf16x4*)(th + (size_t)c1*32 + l8*4);
  if (c2 >= 0) u2 = *(const bf16x4*)(th + (size_t)c2*32 + l8*4);
  if (c3 >= 0) u3 = *(const bf16x4*)(th + (size_t)c3*32 + l8*4);
  while (c0 >= 0){
    int n0 = (i+32<e)? col[i+32] : -1;
    int n1 = (i+40<e)? col[i+40] : -1;
    bf16x4 w0 = {}, w1 = {};
    if (n0 >= 0) w0 = *(const bf16x4*)(th + (size_t)n0*32 + l8*4);
    if (n1 >= 0) w1 = *(const bf16x4*)(th + (size_t)n1*32 + l8*4);
    #pragma unroll
    for (int j=0;j<4;j++) a4[j] += bf2f((unsigned short)u0[j]) + bf2f((unsigned short)u1[j]);
    c0 = c2; c1 = c3; u0 = u2; u1 = u3;
    c2 = n0; c3 = n1; u2 = w0; u3 = w1;
    i += 16;
  }
  #pragma unroll
  for (int j=0;j<4;j++){
    a4[j] += __shfl_down(a4[j], 32);
    a4[j] += __shfl_down(a4[j], 16);
    a4[j] += __shfl_down(a4[j], 8);
  }
  if (lane < 8){
    float ndr = nd[row];
    int half = l8>>2, c0x = (l8&3)*4;
    float4 r;
    r.x = a4[0]*ndr + b3[c0x+0];
    r.y = a4[1]*ndr + b3[c0x+1];
    r.z = a4[2]*ndr + b3[c0x+2];
    r.w = a4[3]*ndr + b3[c0x+3];
    if (half==0) *(float4*)&hout[(size_t)row*16 + c0x] = r;
    int hb = half*16 + c0x;
    hbuf[wave][hb+0]=r.x; hbuf[wave][hb+1]=r.y; hbuf[wave][hb+2]=r.z; hbuf[wave][hb+3]=r.w;
  }
  if (lane < 16){
    int d = lane;
    float e1v = fmaxf(hbuf[wave][d],    0.f);
    float e2v = fmaxf(hbuf[wave][16+d], 0.f);
    float s1 = e1v*e1v, s2 = e2v*e2v;
    #pragma unroll
    for (int off=1; off<16; off<<=1){
      s1 += __shfl_xor(s1, off);
      s2 += __shfl_xor(s2, off);
    }
    float r1 = 1.0f/fmaxf(sqrtf(s1),1e-12f);
    float r2 = 1.0f/fmaxf(sqrtf(s2),1e-12f);
    gbuf[wave][d]    = sigm(e1v*r1);
    gbuf[wave][16+d] = sigm(e2v*r2);
    float vh1=0.f, vh2=0.f;
    #pragma unroll
    for (int e2i=0;e2i<16;e2i++){
      float w = Ws[d*16+e2i];
      vh1 += w*gbuf[wave][e2i];
      vh2 += w*gbuf[wave][16+e2i];
    }
    float q00 = e1v*vh1, q01 = e2v*vh1, q10 = e2v*vh2, q11 = e1v*vh2;
    #pragma unroll
    for (int off=1; off<16; off<<=1){
      q00 += __shfl_xor(q00, off);
      q01 += __shfl_xor(q01, off);
      q10 += __shfl_xor(q10, off);
      q11 += __shfl_xor(q11, off);
    }
    if (lane==0){
      float bb = bdh[0];
      rh [(size_t)row*2+0]=q00+bb; rh [(size_t)row*2+1]=q01+bb;
      rha[(size_t)row*2+0]=q10+bb; rha[(size_t)row*2+1]=q11+bb;
    }
  }
}

// ---------------- launch ----------------
extern "C" void kernel_launch(void* const* d_in, const int* in_sizes, int n_in,
                              void* d_out, int out_size, void* d_ws, size_t ws_size,
                              hipStream_t stream){
  const float* x   = (const float*)d_in[0];
  const float* W1  = (const float*)d_in[1];
  const float* b1  = (const float*)d_in[2];
  const float* W2  = (const float*)d_in[3];
  const float* b2  = (const float*)d_in[4];
  const float* W3  = (const float*)d_in[5];
  const float* b3  = (const float*)d_in[6];
  const float* Wdo = (const float*)d_in[7];
  const float* bdo = (const float*)d_in[8];
  const float* Wdh = (const float*)d_in[9];
  const float* bdh = (const float*)d_in[10];
  const int* ei    = (const int*)d_in[11];
  const int* perm  = (const int*)d_in[12];
  const int* esrc = ei;
  const int* edst = ei + EE;

  char* ws = (char*)d_ws;
  size_t off = 0;
  auto alloc = [&](size_t bytes)->void*{ void* p = ws + off; off += (bytes + 255) & ~(size_t)255; return p; };
  unsigned short* z  = (unsigned short*)alloc((size_t)NN*256*2);
  unsigned short* ob = (unsigned short*)alloc((size_t)2*NN*128*2);
  unsigned short* tz = (unsigned short*)alloc((size_t)NN*128*2);
  unsigned short* th = (unsigned short*)alloc((size_t)NN*32*2);
  int* deg = (int*)alloc((size_t)2*NN*4);
  int* dout_ = deg; int* din_ = deg + NN;
  float* ns = (float*)alloc((size_t)NN*4);
  float* nd = (float*)alloc((size_t)NN*4);
  int* inv  = (int*)alloc((size_t)NN*4);
  float* rn = (float*)alloc((size_t)2*NN*4);
  int* cursor = (int*)alloc((size_t)NN*4);
  int* row_ptr = (int*)alloc((size_t)(NN+1)*4);
  int* colx = (int*)alloc((size_t)EE*4);
  int* chunk = (int*)alloc((size_t)NN*4);
  int* bsum = (int*)alloc((size_t)SCB*4);
  int* bpre = (int*)alloc((size_t)SCB*4);
  unsigned short* W1T = (unsigned short*)alloc((size_t)1024*128*2);
  unsigned short* W2T = (unsigned short*)alloc((size_t)128*128*2);
  unsigned short* WdoB = (unsigned short*)alloc((size_t)128*128*2);
  unsigned short* W3c = (unsigned short*)alloc((size_t)16*128*2);

  float* out_h   = (float*)d_out;
  float* out_ro  = out_h  + (size_t)NN*16;
  float* out_rh  = out_ro + (size_t)NN*2;
  float* out_roa = out_rh + (size_t)NN*2;
  float* out_rha = out_roa+ (size_t)NN*2;

  hipMemsetAsync(deg, 0, (size_t)2*NN*4, stream);
  k_deg_wcvt<<<EE/256 + 648, 256, 0, stream>>>(esrc, edst, dout_, din_,
                                               W1, W2, Wdo, W3, W1T, W2T, WdoB, W3c);
  k_scan1<<<SCB, 1024, 0, stream>>>(din_, chunk, bsum);
  k_scan2<<<1, 128, 0, stream>>>(bsum, bpre, row_ptr);
  k_scan3<<<(NN+255)/256, 256, 0, stream>>>(din_, chunk, bpre, dout_, perm, row_ptr, cursor, ns, nd, inv);

  int gb2 = (2*NN)/64;
  // GC1 GEMM (barrier-free, N-split) + CSR fill, overlapped
  k_g1fill<<<GB1 + FB, 512, 0, stream>>>(x, W1T, tz, esrc, edst, cursor, colx);
  // GC1 aggregation: both encodes via perm-gather from t
  k_agg1<<<(NN+3)/4,256,0,stream>>>(tz, perm, ns, row_ptr, colx, nd, b1, ob);
  // GC2 fused over both encodes, +residual agg (fuses rn)
  k_gemmA<128,0,1><<<gb2,256,0,stream>>>(ob, W2T, z, ns, nullptr, 2*NN,
                                         nullptr, nullptr, nullptr, nullptr, nullptr);
  k_agg128<<<(NN+3)/4,256,0,stream>>>(z, row_ptr, colx, nd, b2, ob, rn);
  // disc GEMM + fused GC3-mult (th) + fused ret_o epilogue
  k_gemmA<128,1,3><<<gb2,256,0,stream>>>(ob, WdoB, nullptr, bdo, rn, 2*NN,
                                         out_ro, out_roa, W3c, ns, th);
  // GC3 agg + fused ret_h
  k_agg16<<<(NN+3)/4,256,0,stream>>>(th, row_ptr, colx, nd, b3, Wdh, bdh, out_h, out_rh, out_rha);
}

// Round 17
// 683.779 us; speedup vs baseline: 1.0991x; 1.0991x over previous
//
#include <hip/hip_runtime.h>
#include <math.h>

#define NN 100000
#define EE 1600000
#define SCB 98   // ceil(NN/1024)
#define GB1 782  // ceil(NN/128)
#define FB 3125  // ceil(EE/512)

typedef __attribute__((ext_vector_type(8))) short bf16x8;
typedef __attribute__((ext_vector_type(4))) short bf16x4;
typedef __attribute__((ext_vector_type(4))) float f32x4;

__device__ __forceinline__ unsigned short f2bf(float x){
  union { float f; unsigned u; } v; v.f = x;
  unsigned r = v.u + 0x7FFFu + ((v.u >> 16) & 1u);
  return (unsigned short)(r >> 16);
}
__device__ __forceinline__ float bf2f(unsigned short h){
  union { unsigned u; float f; } v; v.u = ((unsigned)h) << 16; return v.f;
}
__device__ __forceinline__ float sigm(float x){ return 1.0f/(1.0f+__expf(-x)); }

// light barrier: ds-ops drained, global loads stay in flight (T3/T4; guide §5)
__device__ __forceinline__ void barrier_lds_only(){
  asm volatile("s_waitcnt lgkmcnt(0)" ::: "memory");
  __builtin_amdgcn_s_barrier();
  __builtin_amdgcn_sched_barrier(0);
}

// ---------------- degree + weight convert (merged) ----------------
__global__ __launch_bounds__(256) void k_deg_wcvt(const int* __restrict__ src, const int* __restrict__ dst,
                      int* __restrict__ dout, int* __restrict__ din,
                      const float* __restrict__ W1, const float* __restrict__ W2,
                      const float* __restrict__ Wdo, const float* __restrict__ W3,
                      unsigned short* __restrict__ W1T, unsigned short* __restrict__ W2T,
                      unsigned short* __restrict__ WdoB, unsigned short* __restrict__ W3c){
  int b = blockIdx.x;
  if (b < EE/256){
    int e = b*256 + threadIdx.x;
    atomicAdd(&dout[src[e]],1); atomicAdd(&din[dst[e]],1);
  } else {
    int i = (b - EE/256)*256 + threadIdx.x;
    if (i < 131072){
      int c = i>>13, r = i&8191, col = r>>6, k = c*64 + (r&63);
      W1T[i] = f2bf(W1[(size_t)k*128 + col]);
    } else if (i < 147456){
      int j = i-131072;
      int c = j>>13, r = j&8191, col = r>>6, k = c*64 + (r&63);
      W2T[j] = f2bf(W2[(size_t)k*128 + col]);
    } else if (i < 163840){
      int j = i-147456;
      int c = j>>13, r = j&8191, col = r>>6, k = c*64 + (r&63);
      WdoB[j] = f2bf(Wdo[(size_t)col*128 + k]);   // B = Wdo^T
    } else if (i < 165888){
      int j = i-163840;
      int col = j>>7, k = j&127;
      W3c[j] = f2bf(W3[(size_t)k*16 + col]);
    }
  }
}

// ---------------- parallel scan ----------------
__global__ __launch_bounds__(1024) void k_scan1(const int* __restrict__ din, int* __restrict__ chunk,
                        int* __restrict__ bsum){
  __shared__ int wsum[16];
  int t = threadIdx.x, lane = t & 63, w = t >> 6;
  int i = blockIdx.x*1024 + t;
  int v = (i < NN) ? din[i] : 0;
  int x = v;
  #pragma unroll
  for (int off=1; off<64; off<<=1){
    int y = __shfl_up(x, off);
    if (lane>=off) x += y;
  }
  if (lane==63) wsum[w] = x;
  __syncthreads();
  int pre = 0;
  #pragma unroll
  for (int j=0;j<16;j++) if (j<w) pre += wsum[j];
  int incl = x + pre;
  if (i < NN) chunk[i] = incl;
  if (t == 1023) bsum[blockIdx.x] = incl;
}

__global__ __launch_bounds__(128) void k_scan2(const int* __restrict__ bsum, int* __restrict__ bpre,
                       int* __restrict__ row_ptr){
  __shared__ int w0tot;
  int t = threadIdx.x, lane = t & 63, w = t >> 6;
  int v = (t < SCB) ? bsum[t] : 0;
  int x = v;
  #pragma unroll
  for (int off=1; off<64; off<<=1){
    int y = __shfl_up(x, off);
    if (lane>=off) x += y;
  }
  if (w==0 && lane==63) w0tot = x;
  __syncthreads();
  int incl = x + (w ? w0tot : 0);
  if (t < SCB) bpre[t] = incl - v;
  if (t == 0) row_ptr[0] = 0;
}

__global__ __launch_bounds__(256) void k_scan3(const int* __restrict__ din, const int* __restrict__ chunk,
                       const int* __restrict__ bpre, const int* __restrict__ dout,
                       const int* __restrict__ perm,
                       int* __restrict__ row_ptr, int* __restrict__ cursor,
                       float* __restrict__ ns, float* __restrict__ nd, int* __restrict__ inv){
  int i = blockIdx.x*256 + threadIdx.x;
  if (i < NN){
    int d = din[i];
    int val = chunk[i] + bpre[i>>10];
    row_ptr[i+1] = val;
    cursor[i] = val - d;
    ns[i] = rsqrtf((float)max(dout[i],1));
    nd[i] = rsqrtf((float)max(d,1));
    inv[perm[i]] = i;
  }
}

// ---------------- GC1 GEMM fused with CSR fill (heterogeneous grid) ----------------
// blocks [0, GB1): z scatter for both encodes (sectorized epilogue via LDS);
// blocks [GB1, GB1+FB): CSR fill.
__global__ __launch_bounds__(512,4) void k_g1fill(
    const float* __restrict__ A, const unsigned short* __restrict__ Wc,
    unsigned short* __restrict__ z, const float* __restrict__ ns,
    const int* __restrict__ inv,
    const int* __restrict__ src, const int* __restrict__ dst,
    int* __restrict__ cursor, int* __restrict__ col)
{
  constexpr int NC = 16;
  __shared__ __align__(16) unsigned short As[2*128*72];
  __shared__ __align__(16) unsigned short Bs[2*128*64];
  if (blockIdx.x >= GB1){
    int e = (blockIdx.x - GB1)*512 + threadIdx.x;
    if (e < EE){
      int pos = atomicAdd(&cursor[dst[e]],1);
      col[pos] = src[e];
    }
    return;
  }
  int t = threadIdx.x, wave = t>>6, lane = t&63;
  int row0 = blockIdx.x*128;

  int srow = t>>4;
  int scol4 = (t&15)*4;
  int colB = t>>2;
  int s0B = (t&3)*2;

  f32x4 acc[8] = {};
  float4 S0[4], S1[4];
  bf16x8 w0{}, w1{};

#define ALOAD(SET, CC) { \
  _Pragma("unroll") \
  for (int p=0;p<4;p++){ \
    int rr = min(row0 + p*32 + srow, NN-1); \
    SET[p] = *(const float4*)(A + (size_t)rr*1024 + (CC)*64 + scol4); } }

#define AWRITE(SET, BUF) { \
  _Pragma("unroll") \
  for (int p=0;p<4;p++){ \
    short4 s4; \
    s4.x = (short)f2bf(SET[p].x); s4.y = (short)f2bf(SET[p].y); \
    s4.z = (short)f2bf(SET[p].z); s4.w = (short)f2bf(SET[p].w); \
    *(short4*)&As[(BUF)*9216 + (p*32+srow)*72 + scol4] = s4; } }

#define BLOAD(CC) { \
  const unsigned short* gp = Wc + (size_t)(CC)*8192 + (size_t)t*16; \
  w0 = *(const bf16x8*)(gp); \
  w1 = *(const bf16x8*)(gp+8); }

#define BWRITE(BUF) { \
  unsigned short* bb = &Bs[(BUF)*8192]; \
  *(bf16x8*)&bb[colB*64 + ((s0B     ^ (colB&7))<<3)] = w0; \
  *(bf16x8*)&bb[colB*64 + (((s0B+1) ^ (colB&7))<<3)] = w1; }

  ALOAD(S0, 0);
  BLOAD(0);
  AWRITE(S0, 0);
  BWRITE(0);
  ALOAD(S1, 1);
  BLOAD(1);
  barrier_lds_only();

  int slot0 = lane>>4;
  int c = lane & 15;
  int arow = wave*16 + (lane&15);
  #pragma unroll
  for (int cc=0; cc<NC; ++cc){
    if (cc+2 < NC){
      if (cc&1) { ALOAD(S1, cc+2); } else { ALOAD(S0, cc+2); }
    }
    int cur = cc&1;
    const unsigned short* ab = &As[cur*9216];
    const unsigned short* bb = &Bs[cur*8192];
    {
      bf16x8 af = *(const bf16x8*)&ab[arow*72 + (slot0<<3)];
      #pragma unroll
      for (int j=0;j<8;j++){
        int cj = j*16 + c;
        bf16x8 b = *(const bf16x8*)&bb[cj*64 + ((slot0 ^ (cj&7))<<3)];
        acc[j] = __builtin_amdgcn_mfma_f32_16x16x32_bf16(af, b, acc[j], 0, 0, 0);
      }
    }
    {
      bf16x8 af = *(const bf16x8*)&ab[arow*72 + 32 + (slot0<<3)];
      #pragma unroll
      for (int j=0;j<8;j++){
        int cj = j*16 + c;
        bf16x8 b = *(const bf16x8*)&bb[cj*64 + (((slot0+4) ^ (cj&7))<<3)];
        acc[j] = __builtin_amdgcn_mfma_f32_16x16x32_bf16(af, b, acc[j], 0, 0, 0);
      }
    }
    if (cc+1 < NC){
      int nb = (cc+1)&1;
      if (cc&1) { AWRITE(S0, nb); } else { AWRITE(S1, nb); }
      BWRITE(nb);
      barrier_lds_only();
      if (cc+2 < NC) BLOAD(cc+2);
    }
  }
#undef ALOAD
#undef AWRITE
#undef BLOAD
#undef BWRITE

  // ---- sectorized epilogue: stage raw acc to LDS, re-emit full 64B sectors ----
  __syncthreads();
  {
    // stage: As reused as [128 rows][132 shorts] (pad -> ~2-way bank aliasing)
    int rb_l = wave*16 + (lane>>4)*4;
    #pragma unroll
    for (int j=0;j<8;j++){
      int colx = j*16 + c;
      #pragma unroll
      for (int r=0;r<4;r++)
        As[(rb_l + r)*132 + colx] = f2bf(acc[j][r]);
    }
  }
  __syncthreads();
  {
    // writer: 4 threads per row; instruction q writes one full 64B sector per row
    int rowl = t>>2, seg = t&3;
    int grow = row0 + rowl;
    if (grow < NN){
      float nsr = ns[grow];
      int ir = inv[grow];
      float nsi = ns[ir];
      #pragma unroll
      for (int q=0;q<4;q++){
        bf16x8 v = *(const bf16x8*)&As[rowl*132 + q*32 + seg*8];
        bf16x8 o1, o2;
        #pragma unroll
        for (int k=0;k<8;k++){
          float f = bf2f((unsigned short)v[k]);
          o1[k] = (short)f2bf(f*nsr);
          o2[k] = (short)f2bf(f*nsi);
        }
        *(bf16x8*)&z[(size_t)grow*256 + q*32 + seg*8] = o1;
        *(bf16x8*)&z[(size_t)ir*256 + 128 + q*32 + seg*8] = o2;
      }
    }
  }
}

// ---------------- A-fragment holder (bf16 direct) ----------------
struct ARU { bf16x8 a; };
__device__ __forceinline__ void aload(ARU& r, const unsigned short* p){
  r.a = *(const bf16x8*)p;
}
template<int IM>
__device__ __forceinline__ bf16x8 aconv(const ARU& r, float rs){
  if constexpr (IM==0) return r.a;
  else {
    bf16x8 o;
    #pragma unroll
    for (int i=0;i<8;i++){
      float v = sigm(fmaxf(bf2f((unsigned short)r.a[i]),0.0f)*rs);
      o[i] = (short)f2bf(v);
    }
    return o;
  }
}
__device__ __forceinline__ bf16x8 araw(const ARU& r){ return r.a; }

// ---------------- small-K MFMA GEMM (bf16 A direct) ----------------
template<int KDIM, int IN_MODE, int OUT_MODE>
__global__ __launch_bounds__(256,2) void k_gemmA(
    const unsigned short* __restrict__ A, const unsigned short* __restrict__ Wc,
    unsigned short* __restrict__ out0,
    const float* __restrict__ scale,
    const float* __restrict__ rn, int nrows,
    float* __restrict__ ro, float* __restrict__ roa,
    const unsigned short* __restrict__ W3c, const float* __restrict__ ns2,
    unsigned short* __restrict__ th)
{
  constexpr int NC = KDIM/64;
  __shared__ __align__(16) unsigned short Bs[2*128*64];
  __shared__ __align__(16) unsigned short W3s[OUT_MODE==3 ? 16*128 : 16];
  int t = threadIdx.x, wave = t>>6, lane = t&63;
  int row0 = blockIdx.x*64;
  int arow = row0 + wave*16 + (lane&15);
  int kof = (lane>>4)*8;
  int arow_c = min(arow, nrows-1);
  const unsigned short* ap = A + (size_t)arow_c*KDIM + kof;
  float rscale = 1.0f;
  if constexpr (IN_MODE==1) rscale = rn[arow_c];

  int scol = t>>3;
  int sw = ((t&7) ^ (scol&7))<<3;

  unsigned short* b0 = &Bs[0];
  unsigned short* b1 = &Bs[128*64];
  const unsigned short* bcur = b0; unsigned short* bnxt = b1;

  f32x4 acc[8] = {};
  f32x4 acc2 = {};
  ARU A0a{},A0b{},A1a{},A1b{},A2a{},A2b{};
  bf16x8 w0{},w1{},w2{},w3{};

  {
    const unsigned short* gp = Wc + (size_t)t*8;
    bf16x8 t0 = *(const bf16x8*)(gp);
    bf16x8 t1 = *(const bf16x8*)(gp+2048);
    bf16x8 t2 = *(const bf16x8*)(gp+4096);
    bf16x8 t3 = *(const bf16x8*)(gp+6144);
    *(bf16x8*)&b0[(0*32+scol)*64 + sw] = t0;
    *(bf16x8*)&b0[(1*32+scol)*64 + sw] = t1;
    *(bf16x8*)&b0[(2*32+scol)*64 + sw] = t2;
    *(bf16x8*)&b0[(3*32+scol)*64 + sw] = t3;
  }
  if constexpr (OUT_MODE==3){
    int wc = t>>4, wsl = t&15;
    bf16x8 v = *(const bf16x8*)(W3c + wc*128 + wsl*8);
    *(bf16x8*)&W3s[wc*128 + ((wsl ^ (wc&7))<<3)] = v;
  }
  aload(A0a, ap); aload(A0b, ap+32);
  if (NC>1){
    const unsigned short* gp = Wc + 8192 + (size_t)t*8;
    w0 = *(const bf16x8*)(gp);
    w1 = *(const bf16x8*)(gp+2048);
    w2 = *(const bf16x8*)(gp+4096);
    w3 = *(const bf16x8*)(gp+6144);
    aload(A1a, ap+64); aload(A1b, ap+96);
  }
  __syncthreads();

  int slot0 = lane>>4;
  int c = lane & 15;
  #pragma unroll
  for (int cc=0; cc<NC; ++cc){
    if (cc+2 < NC){
      aload(A2a, ap + (cc+2)*64);
      aload(A2b, ap + (cc+2)*64 + 32);
    }
    {
      bf16x8 af = aconv<IN_MODE>(A0a, rscale);
      #pragma unroll
      for (int j=0;j<8;j++){
        int cj = j*16 + c;
        bf16x8 b = *(const bf16x8*)&bcur[cj*64 + ((slot0 ^ (cj&7))<<3)];
        acc[j] = __builtin_amdgcn_mfma_f32_16x16x32_bf16(af, b, acc[j], 0, 0, 0);
      }
      if constexpr (OUT_MODE==3){
        int sl = cc*8 + slot0;
        bf16x8 b = *(const bf16x8*)&W3s[c*128 + ((sl ^ (c&7))<<3)];
        acc2 = __builtin_amdgcn_mfma_f32_16x16x32_bf16(araw(A0a), b, acc2, 0, 0, 0);
      }
    }
    {
      bf16x8 af = aconv<IN_MODE>(A0b, rscale);
      #pragma unroll
      for (int j=0;j<8;j++){
        int cj = j*16 + c;
        bf16x8 b = *(const bf16x8*)&bcur[cj*64 + (((slot0+4) ^ (cj&7))<<3)];
        acc[j] = __builtin_amdgcn_mfma_f32_16x16x32_bf16(af, b, acc[j], 0, 0, 0);
      }
      if constexpr (OUT_MODE==3){
        int sl = cc*8 + 4 + slot0;
        bf16x8 b = *(const bf16x8*)&W3s[c*128 + ((sl ^ (c&7))<<3)];
        acc2 = __builtin_amdgcn_mfma_f32_16x16x32_bf16(araw(A0b), b, acc2, 0, 0, 0);
      }
    }
    if (cc+1 < NC){
      *(bf16x8*)&bnxt[(0*32+scol)*64 + sw] = w0;
      *(bf16x8*)&bnxt[(1*32+scol)*64 + sw] = w1;
      *(bf16x8*)&bnxt[(2*32+scol)*64 + sw] = w2;
      *(bf16x8*)&bnxt[(3*32+scol)*64 + sw] = w3;
      barrier_lds_only();
      const unsigned short* tmp = bcur; bcur = bnxt; bnxt = (unsigned short*)tmp;
      if (cc+2 < NC){
        const unsigned short* gp = Wc + (size_t)(cc+2)*8192 + (size_t)t*8;
        w0 = *(const bf16x8*)(gp);
        w1 = *(const bf16x8*)(gp+2048);
        w2 = *(const bf16x8*)(gp+4096);
        w3 = *(const bf16x8*)(gp+6144);
      }
    }
    A0a=A1a; A0b=A1b; A1a=A2a; A1b=A2b;
  }

  if constexpr (OUT_MODE==3){
    #pragma unroll
    for (int r=0;r<4;r++){
      int row = row0 + wave*16 + (lane>>4)*4 + r;
      int sidx = row>=NN ? row-NN : row;
      float v = acc2[r]*ns2[sidx];
      size_t tof = row<NN ? (size_t)row*32 + c : (size_t)(row-NN)*32 + 16 + c;
      th[tof] = f2bf(v);
    }
    __syncthreads();
    unsigned short* Os = &Bs[0];
    unsigned short* Oo = &Bs[8192];
    for (int p=t; p<2048; p+=256){
      int r = (p>>4)&63, seg = p&15;
      int row = row0 + r;
      int srcrow = (p<1024) ? row : (row<NN ? row+NN : row-NN);
      unsigned short* dst = (p<1024) ? Os : Oo;
      *(bf16x8*)&dst[r*128 + ((seg ^ (r&7))<<3)] = *(const bf16x8*)&A[(size_t)srcrow*128 + seg*8];
    }
    __syncthreads();
    float bb = scale[0];
    #pragma unroll
    for (int r=0;r<4;r++){
      int lr = wave*16 + (lane>>4)*4 + r;
      float dsame=0.f, doth=0.f;
      #pragma unroll
      for (int j=0;j<8;j++){
        float v = acc[j][r];
        int colj = j*16 + c;
        int idx = lr*128 + (((colj>>3) ^ (lr&7))<<3) + (colj&7);
        dsame += fmaxf(bf2f(Os[idx]),0.f)*v;
        doth  += fmaxf(bf2f(Oo[idx]),0.f)*v;
      }
      #pragma unroll
      for (int off=1; off<16; off<<=1){
        dsame += __shfl_xor(dsame, off);
        doth  += __shfl_xor(doth, off);
      }
      if (c==0){
        int row = row0 + lr;
        if (row < NN){
          ro[(size_t)row*2+0] = dsame + bb;
          ro[(size_t)row*2+1] = doth + bb;
        } else {
          int m = row - NN;
          roa[(size_t)m*2+0] = dsame + bb;
          roa[(size_t)m*2+1] = doth + bb;
        }
      }
    }
  } else {
    int rbase = row0 + wave*16 + (lane>>4)*4;
    #pragma unroll
    for (int j=0;j<8;j++){
      int colx = j*16 + c;
      #pragma unroll
      for (int r=0;r<4;r++){
        int row = rbase + r;
        if (row < nrows){
          float v = acc[j][r];
          int sidx = row >= NN ? row - NN : row;
          size_t zof = row < NN ? (size_t)row*256 + colx : (size_t)(row-NN)*256 + 128 + colx;
          out0[zof] = f2bf(v * scale[sidx]);
        }
      }
    }
  }
}

// ---------------- CSR aggregation, width 128, interleaved z[N][2][128] ----------------
template<bool RESID>
__global__ __launch_bounds__(256) void k_agg128(
  const unsigned short* __restrict__ z,
  const int* __restrict__ row_ptr, const int* __restrict__ col,
  const float* __restrict__ nd, const float* __restrict__ bias,
  unsigned short* __restrict__ ob, float* __restrict__ rn)
{
  int wave = threadIdx.x>>6, lane = threadIdx.x&63;
  int row = blockIdx.x*4 + wave;
  if (row >= NN) return;
  int s = row_ptr[row], e = row_ptr[row+1];
  int es = lane>>5;
  int half = (lane>>4)&1;
  int c8 = (lane&15)*8;
  size_t lof = (size_t)half*128 + c8;
  float acc[8] = {};
  int i = s + es;
  int c0 = (i   < e) ? col[i]   : -1;
  int c1 = (i+2 < e) ? col[i+2] : -1;
  int c2 = (i+4 < e) ? col[i+4] : -1;
  int c3 = (i+6 < e) ? col[i+6] : -1;
  bf16x8 u0 = {}, u1 = {}, u2 = {}, u3 = {};
  if (c0 >= 0) u0 = *(const bf16x8*)(z + (size_t)c0*256 + lof);
  if (c1 >= 0) u1 = *(const bf16x8*)(z + (size_t)c1*256 + lof);
  if (c2 >= 0) u2 = *(const bf16x8*)(z + (size_t)c2*256 + lof);
  if (c3 >= 0) u3 = *(const bf16x8*)(z + (size_t)c3*256 + lof);
  while (c0 >= 0){
    int n0 = (i+8  < e) ? col[i+8]  : -1;
    int n1 = (i+10 < e) ? col[i+10] : -1;
    bf16x8 w0 = {}, w1 = {};
    if (n0 >= 0) w0 = *(const bf16x8*)(z + (size_t)n0*256 + lof);
    if (n1 >= 0) w1 = *(const bf16x8*)(z + (size_t)n1*256 + lof);
    #pragma unroll
    for (int j=0;j<8;j++) acc[j] += bf2f((unsigned short)u0[j]) + bf2f((unsigned short)u1[j]);
    c0 = c2; c1 = c3; u0 = u2; u1 = u3;
    c2 = n0; c3 = n1; u2 = w0; u3 = w1;
    i += 4;
  }
  #pragma unroll
  for (int j=0;j<8;j++) acc[j] += __shfl_down(acc[j], 32);
  if (lane < 32){
    float ndr = nd[row];
    size_t oof = half ? (size_t)(NN+row)*128 + c8 : (size_t)row*128 + c8;
    float ra[8];
    #pragma unroll
    for (int j=0;j<8;j++) ra[j] = acc[j]*ndr + bias[c8+j];
    if constexpr (RESID){
      bf16x8 pv = *(const bf16x8*)(ob + oof);
      #pragma unroll
      for (int j=0;j<8;j++) ra[j] += bf2f((unsigned short)pv[j]);
    }
    bf16x8 wv;
    #pragma unroll
    for (int j=0;j<8;j++) wv[j] = (short)f2bf(ra[j]);
    *(bf16x8*)(ob + oof) = wv;
    if constexpr (RESID){
      float sa = 0.f;
      #pragma unroll
      for (int j=0;j<8;j++){ float x1 = fmaxf(ra[j],0.f); sa += x1*x1; }
      sa += __shfl_down(sa, 8);
      sa += __shfl_down(sa, 4);
      sa += __shfl_down(sa, 2);
      sa += __shfl_down(sa, 1);
      if ((lane&15)==0) rn[half ? NN+row : row] = 1.0f/fmaxf(sqrtf(sa),1e-12f);
    }
  }
}

// ---------------- width-16 aggregation (GC3) + fused ret_h ----------------
__global__ __launch_bounds__(256) void k_agg16(
  const unsigned short* __restrict__ th,
  const int* __restrict__ row_ptr, const int* __restrict__ col,
  const float* __restrict__ nd, const float* __restrict__ b3,
  const float* __restrict__ Wdh, const float* __restrict__ bdh,
  float* __restrict__ hout, float* __restrict__ rh, float* __restrict__ rha)
{
  __shared__ float Ws[256];
  __shared__ float hbuf[4][32];
  __shared__ float gbuf[4][32];
  int t = threadIdx.x;
  Ws[t] = Wdh[t];
  __syncthreads();
  int wave = t>>6, lane = t&63;
  int row = blockIdx.x*4 + wave;
  if (row >= NN) return;
  int s = row_ptr[row], e = row_ptr[row+1];
  int es = lane>>3, l8 = lane&7;
  float a4[4] = {};
  int i = s + es;
  int c0 = (i   <e)? col[i]    : -1;
  int c1 = (i+8 <e)? col[i+8]  : -1;
  int c2 = (i+16<e)? col[i+16] : -1;
  int c3 = (i+24<e)? col[i+24] : -1;
  bf16x4 u0 = {}, u1 = {}, u2 = {}, u3 = {};
  if (c0 >= 0) u0 = *(const bf16x4*)(th + (size_t)c0*32 + l8*4);
  if (c1 >= 0) u1 = *(const bf16x4*)(th + (size_t)c1*32 + l8*4);
  if (c2 >= 0) u2 = *(const bf16x4*)(th + (size_t)c2*32 + l8*4);
  if (c3 >= 0) u3 = *(const bf16x4*)(th + (size_t)c3*32 + l8*4);
  while (c0 >= 0){
    int n0 = (i+32<e)? col[i+32] : -1;
    int n1 = (i+40<e)? col[i+40] : -1;
    bf16x4 w0 = {}, w1 = {};
    if (n0 >= 0) w0 = *(const bf16x4*)(th + (size_t)n0*32 + l8*4);
    if (n1 >= 0) w1 = *(const bf16x4*)(th + (size_t)n1*32 + l8*4);
    #pragma unroll
    for (int j=0;j<4;j++) a4[j] += bf2f((unsigned short)u0[j]) + bf2f((unsigned short)u1[j]);
    c0 = c2; c1 = c3; u0 = u2; u1 = u3;
    c2 = n0; c3 = n1; u2 = w0; u3 = w1;
    i += 16;
  }
  #pragma unroll
  for (int j=0;j<4;j++){
    a4[j] += __shfl_down(a4[j], 32);
    a4[j] += __shfl_down(a4[j], 16);
    a4[j] += __shfl_down(a4[j], 8);
  }
  if (lane < 8){
    float ndr = nd[row];
    int half = l8>>2, c0x = (l8&3)*4;
    float4 r;
    r.x = a4[0]*ndr + b3[c0x+0];
    r.y = a4[1]*ndr + b3[c0x+1];
    r.z = a4[2]*ndr + b3[c0x+2];
    r.w = a4[3]*ndr + b3[c0x+3];
    if (half==0) *(float4*)&hout[(size_t)row*16 + c0x] = r;
    int hb = half*16 + c0x;
    hbuf[wave][hb+0]=r.x; hbuf[wave][hb+1]=r.y; hbuf[wave][hb+2]=r.z; hbuf[wave][hb+3]=r.w;
  }
  if (lane < 16){
    int d = lane;
    float e1v = fmaxf(hbuf[wave][d],    0.f);
    float e2v = fmaxf(hbuf[wave][16+d], 0.f);
    float s1 = e1v*e1v, s2 = e2v*e2v;
    #pragma unroll
    for (int off=1; off<16; off<<=1){
      s1 += __shfl_xor(s1, off);
      s2 += __shfl_xor(s2, off);
    }
    float r1 = 1.0f/fmaxf(sqrtf(s1),1e-12f);
    float r2 = 1.0f/fmaxf(sqrtf(s2),1e-12f);
    gbuf[wave][d]    = sigm(e1v*r1);
    gbuf[wave][16+d] = sigm(e2v*r2);
    float vh1=0.f, vh2=0.f;
    #pragma unroll
    for (int e2i=0;e2i<16;e2i++){
      float w = Ws[d*16+e2i];
      vh1 += w*gbuf[wave][e2i];
      vh2 += w*gbuf[wave][16+e2i];
    }
    float q00 = e1v*vh1, q01 = e2v*vh1, q10 = e2v*vh2, q11 = e1v*vh2;
    #pragma unroll
    for (int off=1; off<16; off<<=1){
      q00 += __shfl_xor(q00, off);
      q01 += __shfl_xor(q01, off);
      q10 += __shfl_xor(q10, off);
      q11 += __shfl_xor(q11, off);
    }
    if (lane==0){
      float bb = bdh[0];
      rh [(size_t)row*2+0]=q00+bb; rh [(size_t)row*2+1]=q01+bb;
      rha[(size_t)row*2+0]=q10+bb; rha[(size_t)row*2+1]=q11+bb;
    }
  }
}

// ---------------- launch ----------------
extern "C" void kernel_launch(void* const* d_in, const int* in_sizes, int n_in,
                              void* d_out, int out_size, void* d_ws, size_t ws_size,
                              hipStream_t stream){
  const float* x   = (const float*)d_in[0];
  const float* W1  = (const float*)d_in[1];
  const float* b1  = (const float*)d_in[2];
  const float* W2  = (const float*)d_in[3];
  const float* b2  = (const float*)d_in[4];
  const float* W3  = (const float*)d_in[5];
  const float* b3  = (const float*)d_in[6];
  const float* Wdo = (const float*)d_in[7];
  const float* bdo = (const float*)d_in[8];
  const float* Wdh = (const float*)d_in[9];
  const float* bdh = (const float*)d_in[10];
  const int* ei    = (const int*)d_in[11];
  const int* perm  = (const int*)d_in[12];
  const int* esrc = ei;
  const int* edst = ei + EE;

  char* ws = (char*)d_ws;
  size_t off = 0;
  auto alloc = [&](size_t bytes)->void*{ void* p = ws + off; off += (bytes + 255) & ~(size_t)255; return p; };
  unsigned short* z  = (unsigned short*)alloc((size_t)NN*256*2);
  unsigned short* ob = (unsigned short*)alloc((size_t)2*NN*128*2);
  unsigned short* th = (unsigned short*)alloc((size_t)NN*32*2);
  int* deg = (int*)alloc((size_t)2*NN*4);
  int* dout_ = deg; int* din_ = deg + NN;
  float* ns = (float*)alloc((size_t)NN*4);
  float* nd = (float*)alloc((size_t)NN*4);
  int* inv  = (int*)alloc((size_t)NN*4);
  float* rn = (float*)alloc((size_t)2*NN*4);
  int* cursor = (int*)alloc((size_t)NN*4);
  int* row_ptr = (int*)alloc((size_t)(NN+1)*4);
  int* colx = (int*)alloc((size_t)EE*4);
  int* chunk = (int*)alloc((size_t)NN*4);
  int* bsum = (int*)alloc((size_t)SCB*4);
  int* bpre = (int*)alloc((size_t)SCB*4);
  unsigned short* W1T = (unsigned short*)alloc((size_t)1024*128*2);
  unsigned short* W2T = (unsigned short*)alloc((size_t)128*128*2);
  unsigned short* WdoB = (unsigned short*)alloc((size_t)128*128*2);
  unsigned short* W3c = (unsigned short*)alloc((size_t)16*128*2);

  float* out_h   = (float*)d_out;
  float* out_ro  = out_h  + (size_t)NN*16;
  float* out_rh  = out_ro + (size_t)NN*2;
  float* out_roa = out_rh + (size_t)NN*2;
  float* out_rha = out_roa+ (size_t)NN*2;

  hipMemsetAsync(deg, 0, (size_t)2*NN*4, stream);
  k_deg_wcvt<<<EE/256 + 648, 256, 0, stream>>>(esrc, edst, dout_, din_,
                                               W1, W2, Wdo, W3, W1T, W2T, WdoB, W3c);
  k_scan1<<<SCB, 1024, 0, stream>>>(din_, chunk, bsum);
  k_scan2<<<1, 128, 0, stream>>>(bsum, bpre, row_ptr);
  k_scan3<<<(NN+255)/256, 256, 0, stream>>>(din_, chunk, bpre, dout_, perm, row_ptr, cursor, ns, nd, inv);

  int gb2 = (2*NN)/64;
  // GC1 GEMM + CSR fill, overlapped in one heterogeneous grid
  k_g1fill<<<GB1 + FB, 512, 0, stream>>>(x, W1T, z, ns, inv, esrc, edst, cursor, colx);
  k_agg128<false><<<(NN+3)/4,256,0,stream>>>(z, row_ptr, colx, nd, b1, ob, nullptr);
  // GC2 fused over both encodes, +residual agg (fuses rn)
  k_gemmA<128,0,1><<<gb2,256,0,stream>>>(ob, W2T, z, ns, nullptr, 2*NN,
                                         nullptr, nullptr, nullptr, nullptr, nullptr);
  k_agg128<true><<<(NN+3)/4,256,0,stream>>>(z, row_ptr, colx, nd, b2, ob, rn);
  // disc GEMM + fused GC3-mult (th) + fused ret_o epilogue
  k_gemmA<128,1,3><<<gb2,256,0,stream>>>(ob, WdoB, nullptr, bdo, rn, 2*NN,
                                         out_ro, out_roa, W3c, ns, th);
  // GC3 agg + fused ret_h
  k_agg16<<<(NN+3)/4,256,0,stream>>>(th, row_ptr, colx, nd, b3, Wdh, bdh, out_h, out_rh, out_rha);
}

// Round 18
// 649.930 us; speedup vs baseline: 1.1564x; 1.0521x over previous
//
#include <hip/hip_runtime.h>
#include <math.h>

#define NN 100000
#define EE 1600000
#define SCB 98    // ceil(NN/1024)
#define NG1 391   // GEMM blocks per half (2*391*128 >= NN)
#define FB 3125   // ceil(EE/512)

typedef __attribute__((ext_vector_type(8))) short bf16x8;
typedef __attribute__((ext_vector_type(4))) short bf16x4;
typedef __attribute__((ext_vector_type(4))) float f32x4;

__device__ __forceinline__ unsigned short f2bf(float x){
  union { float f; unsigned u; } v; v.f = x;
  unsigned r = v.u + 0x7FFFu + ((v.u >> 16) & 1u);
  return (unsigned short)(r >> 16);
}
__device__ __forceinline__ float bf2f(unsigned short h){
  union { unsigned u; float f; } v; v.u = ((unsigned)h) << 16; return v.f;
}
__device__ __forceinline__ float sigm(float x){ return 1.0f/(1.0f+__expf(-x)); }

// light barrier: ds-ops drained, global loads stay in flight (T3/T4; guide §5)
__device__ __forceinline__ void barrier_lds_only(){
  asm volatile("s_waitcnt lgkmcnt(0)" ::: "memory");
  __builtin_amdgcn_s_barrier();
  __builtin_amdgcn_sched_barrier(0);
}

// ---------------- weight convert (standalone, small) ----------------
__global__ __launch_bounds__(256) void k_wcvt(
                      const float* __restrict__ W1, const float* __restrict__ W2,
                      const float* __restrict__ Wdo, const float* __restrict__ W3,
                      unsigned short* __restrict__ W1T, unsigned short* __restrict__ W2T,
                      unsigned short* __restrict__ WdoB, unsigned short* __restrict__ W3c){
  int i = blockIdx.x*256 + threadIdx.x;
  if (i < 131072){
    int c = i>>13, r = i&8191, col = r>>6, k = c*64 + (r&63);
    W1T[i] = f2bf(W1[(size_t)k*128 + col]);
  } else if (i < 147456){
    int j = i-131072;
    int c = j>>13, r = j&8191, col = r>>6, k = c*64 + (r&63);
    W2T[j] = f2bf(W2[(size_t)k*128 + col]);
  } else if (i < 163840){
    int j = i-147456;
    int c = j>>13, r = j&8191, col = r>>6, k = c*64 + (r&63);
    WdoB[j] = f2bf(Wdo[(size_t)col*128 + k]);   // B = Wdo^T
  } else if (i < 165888){
    int j = i-163840;
    int col = j>>7, k = j&127;
    W3c[j] = f2bf(W3[(size_t)k*16 + col]);
  }
}

// ---------------- parallel scan ----------------
__global__ __launch_bounds__(1024) void k_scan1(const int* __restrict__ din, int* __restrict__ chunk,
                        int* __restrict__ bsum){
  __shared__ int wsum[16];
  int t = threadIdx.x, lane = t & 63, w = t >> 6;
  int i = blockIdx.x*1024 + t;
  int v = (i < NN) ? din[i] : 0;
  int x = v;
  #pragma unroll
  for (int off=1; off<64; off<<=1){
    int y = __shfl_up(x, off);
    if (lane>=off) x += y;
  }
  if (lane==63) wsum[w] = x;
  __syncthreads();
  int pre = 0;
  #pragma unroll
  for (int j=0;j<16;j++) if (j<w) pre += wsum[j];
  int incl = x + pre;
  if (i < NN) chunk[i] = incl;
  if (t == 1023) bsum[blockIdx.x] = incl;
}

__global__ __launch_bounds__(128) void k_scan2(const int* __restrict__ bsum, int* __restrict__ bpre,
                       int* __restrict__ row_ptr){
  __shared__ int w0tot;
  int t = threadIdx.x, lane = t & 63, w = t >> 6;
  int v = (t < SCB) ? bsum[t] : 0;
  int x = v;
  #pragma unroll
  for (int off=1; off<64; off<<=1){
    int y = __shfl_up(x, off);
    if (lane>=off) x += y;
  }
  if (w==0 && lane==63) w0tot = x;
  __syncthreads();
  int incl = x + (w ? w0tot : 0);
  if (t < SCB) bpre[t] = incl - v;
  if (t == 0) row_ptr[0] = 0;
}

__global__ __launch_bounds__(256) void k_scan3(const int* __restrict__ din, const int* __restrict__ chunk,
                       const int* __restrict__ bpre, const int* __restrict__ dout,
                       const int* __restrict__ perm,
                       int* __restrict__ row_ptr, int* __restrict__ cursor,
                       float* __restrict__ ns, float* __restrict__ nd, int* __restrict__ inv){
  int i = blockIdx.x*256 + threadIdx.x;
  if (i < NN){
    int d = din[i];
    int val = chunk[i] + bpre[i>>10];
    row_ptr[i+1] = val;
    cursor[i] = val - d;
    ns[i] = rsqrtf((float)max(dout[i],1));
    nd[i] = rsqrtf((float)max(d,1));
    inv[perm[i]] = i;
  }
}

// ---------------- GC1 GEMM half + tail job (heterogeneous grid) ----------------
// TAIL=0: tail blocks do degree counting; TAIL=1: tail blocks do CSR fill
// (colx2[pos] = {src, perm[src]}). GEMM blocks write raw t (no ns/inv dep).
template<int TAIL>
__global__ __launch_bounds__(512,4) void k_g1(
    const float* __restrict__ A, const unsigned short* __restrict__ Wc,
    unsigned short* __restrict__ tz,
    const int* __restrict__ src, const int* __restrict__ dst,
    int* __restrict__ p0, int* __restrict__ p1,
    int2* __restrict__ colx2, const int* __restrict__ perm, int rowBase)
{
  constexpr int NC = 16;
  __shared__ __align__(16) unsigned short As[2*128*72];
  __shared__ __align__(16) unsigned short Bs[2*128*64];
  if (blockIdx.x >= NG1){
    int e = (blockIdx.x - NG1)*512 + threadIdx.x;
    if (e < EE){
      if constexpr (TAIL==0){
        atomicAdd(&p0[src[e]],1);
        atomicAdd(&p1[dst[e]],1);
      } else {
        int s = src[e];
        int pos = atomicAdd(&p0[dst[e]],1);
        colx2[pos] = make_int2(s, perm[s]);
      }
    }
    return;
  }
  int t = threadIdx.x, wave = t>>6, lane = t&63;
  int row0 = (rowBase + blockIdx.x)*128;

  int srow = t>>4;
  int scol4 = (t&15)*4;
  int colB = t>>2;
  int s0B = (t&3)*2;

  f32x4 acc[8] = {};
  float4 S0[4], S1[4];
  bf16x8 w0{}, w1{};

#define ALOAD(SET, CC) { \
  _Pragma("unroll") \
  for (int p=0;p<4;p++){ \
    int rr = min(row0 + p*32 + srow, NN-1); \
    SET[p] = *(const float4*)(A + (size_t)rr*1024 + (CC)*64 + scol4); } }

#define AWRITE(SET, BUF) { \
  _Pragma("unroll") \
  for (int p=0;p<4;p++){ \
    short4 s4; \
    s4.x = (short)f2bf(SET[p].x); s4.y = (short)f2bf(SET[p].y); \
    s4.z = (short)f2bf(SET[p].z); s4.w = (short)f2bf(SET[p].w); \
    *(short4*)&As[(BUF)*9216 + (p*32+srow)*72 + scol4] = s4; } }

#define BLOAD(CC) { \
  const unsigned short* gp = Wc + (size_t)(CC)*8192 + (size_t)t*16; \
  w0 = *(const bf16x8*)(gp); \
  w1 = *(const bf16x8*)(gp+8); }

#define BWRITE(BUF) { \
  unsigned short* bb = &Bs[(BUF)*8192]; \
  *(bf16x8*)&bb[colB*64 + ((s0B     ^ (colB&7))<<3)] = w0; \
  *(bf16x8*)&bb[colB*64 + (((s0B+1) ^ (colB&7))<<3)] = w1; }

  ALOAD(S0, 0);
  BLOAD(0);
  AWRITE(S0, 0);
  BWRITE(0);
  ALOAD(S1, 1);
  BLOAD(1);
  barrier_lds_only();

  int slot0 = lane>>4;
  int c = lane & 15;
  int arow = wave*16 + (lane&15);
  #pragma unroll
  for (int cc=0; cc<NC; ++cc){
    if (cc+2 < NC){
      if (cc&1) { ALOAD(S1, cc+2); } else { ALOAD(S0, cc+2); }
    }
    int cur = cc&1;
    const unsigned short* ab = &As[cur*9216];
    const unsigned short* bb = &Bs[cur*8192];
    {
      bf16x8 af = *(const bf16x8*)&ab[arow*72 + (slot0<<3)];
      #pragma unroll
      for (int j=0;j<8;j++){
        int cj = j*16 + c;
        bf16x8 b = *(const bf16x8*)&bb[cj*64 + ((slot0 ^ (cj&7))<<3)];
        acc[j] = __builtin_amdgcn_mfma_f32_16x16x32_bf16(af, b, acc[j], 0, 0, 0);
      }
    }
    {
      bf16x8 af = *(const bf16x8*)&ab[arow*72 + 32 + (slot0<<3)];
      #pragma unroll
      for (int j=0;j<8;j++){
        int cj = j*16 + c;
        bf16x8 b = *(const bf16x8*)&bb[cj*64 + (((slot0+4) ^ (cj&7))<<3)];
        acc[j] = __builtin_amdgcn_mfma_f32_16x16x32_bf16(af, b, acc[j], 0, 0, 0);
      }
    }
    if (cc+1 < NC){
      int nb = (cc+1)&1;
      if (cc&1) { AWRITE(S0, nb); } else { AWRITE(S1, nb); }
      BWRITE(nb);
      barrier_lds_only();
      if (cc+2 < NC) BLOAD(cc+2);
    }
  }
#undef ALOAD
#undef AWRITE
#undef BLOAD
#undef BWRITE

  // epilogue: coalesced write of raw GEMM output (no scale, no scatter)
  int rbase = row0 + wave*16 + (lane>>4)*4;
  #pragma unroll
  for (int j=0;j<8;j++){
    int colx = j*16 + c;
    #pragma unroll
    for (int r=0;r<4;r++){
      int row = rbase + r;
      if (row < NN) tz[(size_t)row*128 + colx] = f2bf(acc[j][r]);
    }
  }
}

// ---------------- GC1 aggregation from t/colx2/ns (both encodes) ----------------
// wave per row; 2 edge-slots x (2 halves x 16 lanes); 2-deep pipeline.
// half 0: t[src]*ns[src];  half 1: t[perm[src]]*ns[src]  (perm pre-folded in colx2.y)
__global__ __launch_bounds__(256) void k_agg1(
  const unsigned short* __restrict__ tz,
  const float* __restrict__ ns,
  const int* __restrict__ row_ptr, const int2* __restrict__ colx2,
  const float* __restrict__ nd, const float* __restrict__ bias,
  unsigned short* __restrict__ ob)
{
  int wave = threadIdx.x>>6, lane = threadIdx.x&63;
  int row = blockIdx.x*4 + wave;
  if (row >= NN) return;
  int s = row_ptr[row], e = row_ptr[row+1];
  int es = lane>>5;
  int half = (lane>>4)&1;
  int c8 = (lane&15)*8;
  float acc[8] = {};
  bf16x8 zer = {};
  int i = s + es;

#define FETCH1(IDX, U, F) { \
  if ((IDX) < e){ \
    int2 cc = colx2[(IDX)]; \
    int rr = half ? cc.y : cc.x; \
    F = ns[cc.x]; \
    U = *(const bf16x8*)(tz + (size_t)rr*128 + c8); \
  } else { F = 0.0f; U = zer; } }

  bf16x8 u0, u1, u2, u3;
  float f0, f1, f2, f3;
  FETCH1(i,   u0, f0);
  FETCH1(i+2, u1, f1);
  FETCH1(i+4, u2, f2);
  FETCH1(i+6, u3, f3);
  while (i < e){
    bf16x8 w0, w1; float g0, g1;
    FETCH1(i+8,  w0, g0);
    FETCH1(i+10, w1, g1);
    #pragma unroll
    for (int j=0;j<8;j++)
      acc[j] += bf2f((unsigned short)u0[j])*f0 + bf2f((unsigned short)u1[j])*f1;
    u0=u2; f0=f2; u1=u3; f1=f3;
    u2=w0; f2=g0; u3=w1; f3=g1;
    i += 4;
  }
#undef FETCH1
  #pragma unroll
  for (int j=0;j<8;j++) acc[j] += __shfl_down(acc[j], 32);
  if (lane < 32){
    float ndr = nd[row];
    size_t oof = half ? (size_t)(NN+row)*128 + c8 : (size_t)row*128 + c8;
    bf16x8 wv;
    #pragma unroll
    for (int j=0;j<8;j++) wv[j] = (short)f2bf(acc[j]*ndr + bias[c8+j]);
    *(bf16x8*)(ob + oof) = wv;
  }
}

// ---------------- A-fragment holder (bf16 direct) ----------------
struct ARU { bf16x8 a; };
__device__ __forceinline__ void aload(ARU& r, const unsigned short* p){
  r.a = *(const bf16x8*)p;
}
template<int IM>
__device__ __forceinline__ bf16x8 aconv(const ARU& r, float rs){
  if constexpr (IM==0) return r.a;
  else {
    bf16x8 o;
    #pragma unroll
    for (int i=0;i<8;i++){
      float v = sigm(fmaxf(bf2f((unsigned short)r.a[i]),0.0f)*rs);
      o[i] = (short)f2bf(v);
    }
    return o;
  }
}
__device__ __forceinline__ bf16x8 araw(const ARU& r){ return r.a; }

// ---------------- small-K MFMA GEMM (bf16 A direct) ----------------
template<int KDIM, int IN_MODE, int OUT_MODE>
__global__ __launch_bounds__(256,2) void k_gemmA(
    const unsigned short* __restrict__ A, const unsigned short* __restrict__ Wc,
    unsigned short* __restrict__ out0,
    const float* __restrict__ scale,
    const float* __restrict__ rn, int nrows,
    float* __restrict__ ro, float* __restrict__ roa,
    const unsigned short* __restrict__ W3c, const float* __restrict__ ns2,
    unsigned short* __restrict__ th)
{
  constexpr int NC = KDIM/64;
  __shared__ __align__(16) unsigned short Bs[2*128*64];
  __shared__ __align__(16) unsigned short W3s[OUT_MODE==3 ? 16*128 : 16];
  int t = threadIdx.x, wave = t>>6, lane = t&63;
  int row0 = blockIdx.x*64;
  int arow = row0 + wave*16 + (lane&15);
  int kof = (lane>>4)*8;
  int arow_c = min(arow, nrows-1);
  const unsigned short* ap = A + (size_t)arow_c*KDIM + kof;
  float rscale = 1.0f;
  if constexpr (IN_MODE==1) rscale = rn[arow_c];

  int scol = t>>3;
  int sw = ((t&7) ^ (scol&7))<<3;

  unsigned short* b0 = &Bs[0];
  unsigned short* b1 = &Bs[128*64];
  const unsigned short* bcur = b0; unsigned short* bnxt = b1;

  f32x4 acc[8] = {};
  f32x4 acc2 = {};
  ARU A0a{},A0b{},A1a{},A1b{},A2a{},A2b{};
  bf16x8 w0{},w1{},w2{},w3{};

  {
    const unsigned short* gp = Wc + (size_t)t*8;
    bf16x8 t0 = *(const bf16x8*)(gp);
    bf16x8 t1 = *(const bf16x8*)(gp+2048);
    bf16x8 t2 = *(const bf16x8*)(gp+4096);
    bf16x8 t3 = *(const bf16x8*)(gp+6144);
    *(bf16x8*)&b0[(0*32+scol)*64 + sw] = t0;
    *(bf16x8*)&b0[(1*32+scol)*64 + sw] = t1;
    *(bf16x8*)&b0[(2*32+scol)*64 + sw] = t2;
    *(bf16x8*)&b0[(3*32+scol)*64 + sw] = t3;
  }
  if constexpr (OUT_MODE==3){
    int wc = t>>4, wsl = t&15;
    bf16x8 v = *(const bf16x8*)(W3c + wc*128 + wsl*8);
    *(bf16x8*)&W3s[wc*128 + ((wsl ^ (wc&7))<<3)] = v;
  }
  aload(A0a, ap); aload(A0b, ap+32);
  if (NC>1){
    const unsigned short* gp = Wc + 8192 + (size_t)t*8;
    w0 = *(const bf16x8*)(gp);
    w1 = *(const bf16x8*)(gp+2048);
    w2 = *(const bf16x8*)(gp+4096);
    w3 = *(const bf16x8*)(gp+6144);
    aload(A1a, ap+64); aload(A1b, ap+96);
  }
  __syncthreads();

  int slot0 = lane>>4;
  int c = lane & 15;
  #pragma unroll
  for (int cc=0; cc<NC; ++cc){
    if (cc+2 < NC){
      aload(A2a, ap + (cc+2)*64);
      aload(A2b, ap + (cc+2)*64 + 32);
    }
    {
      bf16x8 af = aconv<IN_MODE>(A0a, rscale);
      #pragma unroll
      for (int j=0;j<8;j++){
        int cj = j*16 + c;
        bf16x8 b = *(const bf16x8*)&bcur[cj*64 + ((slot0 ^ (cj&7))<<3)];
        acc[j] = __builtin_amdgcn_mfma_f32_16x16x32_bf16(af, b, acc[j], 0, 0, 0);
      }
      if constexpr (OUT_MODE==3){
        int sl = cc*8 + slot0;
        bf16x8 b = *(const bf16x8*)&W3s[c*128 + ((sl ^ (c&7))<<3)];
        acc2 = __builtin_amdgcn_mfma_f32_16x16x32_bf16(araw(A0a), b, acc2, 0, 0, 0);
      }
    }
    {
      bf16x8 af = aconv<IN_MODE>(A0b, rscale);
      #pragma unroll
      for (int j=0;j<8;j++){
        int cj = j*16 + c;
        bf16x8 b = *(const bf16x8*)&bcur[cj*64 + (((slot0+4) ^ (cj&7))<<3)];
        acc[j] = __builtin_amdgcn_mfma_f32_16x16x32_bf16(af, b, acc[j], 0, 0, 0);
      }
      if constexpr (OUT_MODE==3){
        int sl = cc*8 + 4 + slot0;
        bf16x8 b = *(const bf16x8*)&W3s[c*128 + ((sl ^ (c&7))<<3)];
        acc2 = __builtin_amdgcn_mfma_f32_16x16x32_bf16(araw(A0b), b, acc2, 0, 0, 0);
      }
    }
    if (cc+1 < NC){
      *(bf16x8*)&bnxt[(0*32+scol)*64 + sw] = w0;
      *(bf16x8*)&bnxt[(1*32+scol)*64 + sw] = w1;
      *(bf16x8*)&bnxt[(2*32+scol)*64 + sw] = w2;
      *(bf16x8*)&bnxt[(3*32+scol)*64 + sw] = w3;
      barrier_lds_only();
      const unsigned short* tmp = bcur; bcur = bnxt; bnxt = (unsigned short*)tmp;
      if (cc+2 < NC){
        const unsigned short* gp = Wc + (size_t)(cc+2)*8192 + (size_t)t*8;
        w0 = *(const bf16x8*)(gp);
        w1 = *(const bf16x8*)(gp+2048);
        w2 = *(const bf16x8*)(gp+4096);
        w3 = *(const bf16x8*)(gp+6144);
      }
    }
    A0a=A1a; A0b=A1b; A1a=A2a; A1b=A2b;
  }

  if constexpr (OUT_MODE==3){
    #pragma unroll
    for (int r=0;r<4;r++){
      int row = row0 + wave*16 + (lane>>4)*4 + r;
      int sidx = row>=NN ? row-NN : row;
      float v = acc2[r]*ns2[sidx];
      size_t tof = row<NN ? (size_t)row*32 + c : (size_t)(row-NN)*32 + 16 + c;
      th[tof] = f2bf(v);
    }
    __syncthreads();
    unsigned short* Os = &Bs[0];
    unsigned short* Oo = &Bs[8192];
    for (int p=t; p<2048; p+=256){
      int r = (p>>4)&63, seg = p&15;
      int row = row0 + r;
      int srcrow = (p<1024) ? row : (row<NN ? row+NN : row-NN);
      unsigned short* dst = (p<1024) ? Os : Oo;
      *(bf16x8*)&dst[r*128 + ((seg ^ (r&7))<<3)] = *(const bf16x8*)&A[(size_t)srcrow*128 + seg*8];
    }
    __syncthreads();
    float bb = scale[0];
    #pragma unroll
    for (int r=0;r<4;r++){
      int lr = wave*16 + (lane>>4)*4 + r;
      float dsame=0.f, doth=0.f;
      #pragma unroll
      for (int j=0;j<8;j++){
        float v = acc[j][r];
        int colj = j*16 + c;
        int idx = lr*128 + (((colj>>3) ^ (lr&7))<<3) + (colj&7);
        dsame += fmaxf(bf2f(Os[idx]),0.f)*v;
        doth  += fmaxf(bf2f(Oo[idx]),0.f)*v;
      }
      #pragma unroll
      for (int off=1; off<16; off<<=1){
        dsame += __shfl_xor(dsame, off);
        doth  += __shfl_xor(doth, off);
      }
      if (c==0){
        int row = row0 + lr;
        if (row < NN){
          ro[(size_t)row*2+0] = dsame + bb;
          ro[(size_t)row*2+1] = doth + bb;
        } else {
          int m = row - NN;
          roa[(size_t)m*2+0] = dsame + bb;
          roa[(size_t)m*2+1] = doth + bb;
        }
      }
    }
  } else {
    int rbase = row0 + wave*16 + (lane>>4)*4;
    #pragma unroll
    for (int j=0;j<8;j++){
      int colx = j*16 + c;
      #pragma unroll
      for (int r=0;r<4;r++){
        int row = rbase + r;
        if (row < nrows){
          float v = acc[j][r];
          int sidx = row >= NN ? row - NN : row;
          size_t zof = row < NN ? (size_t)row*256 + colx : (size_t)(row-NN)*256 + 128 + colx;
          out0[zof] = f2bf(v * scale[sidx]);
        }
      }
    }
  }
}

// ---------------- CSR aggregation (GC2, residual), interleaved z[N][2][128] ----------------
__global__ __launch_bounds__(256) void k_agg128(
  const unsigned short* __restrict__ z,
  const int* __restrict__ row_ptr, const int2* __restrict__ colx2,
  const float* __restrict__ nd, const float* __restrict__ bias,
  unsigned short* __restrict__ ob, float* __restrict__ rn)
{
  int wave = threadIdx.x>>6, lane = threadIdx.x&63;
  int row = blockIdx.x*4 + wave;
  if (row >= NN) return;
  int s = row_ptr[row], e = row_ptr[row+1];
  int es = lane>>5;
  int half = (lane>>4)&1;
  int c8 = (lane&15)*8;
  size_t lof = (size_t)half*128 + c8;
  float acc[8] = {};
  int i = s + es;
  int c0 = (i   < e) ? colx2[i].x   : -1;
  int c1 = (i+2 < e) ? colx2[i+2].x : -1;
  int c2 = (i+4 < e) ? colx2[i+4].x : -1;
  int c3 = (i+6 < e) ? colx2[i+6].x : -1;
  bf16x8 u0 = {}, u1 = {}, u2 = {}, u3 = {};
  if (c0 >= 0) u0 = *(const bf16x8*)(z + (size_t)c0*256 + lof);
  if (c1 >= 0) u1 = *(const bf16x8*)(z + (size_t)c1*256 + lof);
  if (c2 >= 0) u2 = *(const bf16x8*)(z + (size_t)c2*256 + lof);
  if (c3 >= 0) u3 = *(const bf16x8*)(z + (size_t)c3*256 + lof);
  while (c0 >= 0){
    int n0 = (i+8  < e) ? colx2[i+8].x  : -1;
    int n1 = (i+10 < e) ? colx2[i+10].x : -1;
    bf16x8 w0 = {}, w1 = {};
    if (n0 >= 0) w0 = *(const bf16x8*)(z + (size_t)n0*256 + lof);
    if (n1 >= 0) w1 = *(const bf16x8*)(z + (size_t)n1*256 + lof);
    #pragma unroll
    for (int j=0;j<8;j++) acc[j] += bf2f((unsigned short)u0[j]) + bf2f((unsigned short)u1[j]);
    c0 = c2; c1 = c3; u0 = u2; u1 = u3;
    c2 = n0; c3 = n1; u2 = w0; u3 = w1;
    i += 4;
  }
  #pragma unroll
  for (int j=0;j<8;j++) acc[j] += __shfl_down(acc[j], 32);
  if (lane < 32){
    float ndr = nd[row];
    size_t oof = half ? (size_t)(NN+row)*128 + c8 : (size_t)row*128 + c8;
    float ra[8];
    #pragma unroll
    for (int j=0;j<8;j++) ra[j] = acc[j]*ndr + bias[c8+j];
    {
      bf16x8 pv = *(const bf16x8*)(ob + oof);
      #pragma unroll
      for (int j=0;j<8;j++) ra[j] += bf2f((unsigned short)pv[j]);
    }
    bf16x8 wv;
    #pragma unroll
    for (int j=0;j<8;j++) wv[j] = (short)f2bf(ra[j]);
    *(bf16x8*)(ob + oof) = wv;
    {
      float sa = 0.f;
      #pragma unroll
      for (int j=0;j<8;j++){ float x1 = fmaxf(ra[j],0.f); sa += x1*x1; }
      sa += __shfl_down(sa, 8);
      sa += __shfl_down(sa, 4);
      sa += __shfl_down(sa, 2);
      sa += __shfl_down(sa, 1);
      if ((lane&15)==0) rn[half ? NN+row : row] = 1.0f/fmaxf(sqrtf(sa),1e-12f);
    }
  }
}

// ---------------- width-16 aggregation (GC3) + fused ret_h ----------------
__global__ __launch_bounds__(256) void k_agg16(
  const unsigned short* __restrict__ th,
  const int* __restrict__ row_ptr, const int2* __restrict__ colx2,
  const float* __restrict__ nd, const float* __restrict__ b3,
  const float* __restrict__ Wdh, const float* __restrict__ bdh,
  float* __restrict__ hout, float* __restrict__ rh, float* __restrict__ rha)
{
  __shared__ float Ws[256];
  __shared__ float hbuf[4][32];
  __shared__ float gbuf[4][32];
  int t = threadIdx.x;
  Ws[t] = Wdh[t];
  __syncthreads();
  int wave = t>>6, lane = t&63;
  int row = blockIdx.x*4 + wave;
  if (row >= NN) return;
  int s = row_ptr[row], e = row_ptr[row+1];
  int es = lane>>3, l8 = lane&7;
  float a4[4] = {};
  int i = s + es;
  int c0 = (i   <e)? colx2[i].x    : -1;
  int c1 = (i+8 <e)? colx2[i+8].x  : -1;
  int c2 = (i+16<e)? colx2[i+16].x : -1;
  int c3 = (i+24<e)? colx2[i+24].x : -1;
  bf16x4 u0 = {}, u1 = {}, u2 = {}, u3 = {};
  if (c0 >= 0) u0 = *(const bf16x4*)(th + (size_t)c0*32 + l8*4);
  if (c1 >= 0) u1 = *(const bf16x4*)(th + (size_t)c1*32 + l8*4);
  if (c2 >= 0) u2 = *(const bf16x4*)(th + (size_t)c2*32 + l8*4);
  if (c3 >= 0) u3 = *(const bf16x4*)(th + (size_t)c3*32 + l8*4);
  while (c0 >= 0){
    int n0 = (i+32<e)? colx2[i+32].x : -1;
    int n1 = (i+40<e)? colx2[i+40].x : -1;
    bf16x4 w0 = {}, w1 = {};
    if (n0 >= 0) w0 = *(const bf16x4*)(th + (size_t)n0*32 + l8*4);
    if (n1 >= 0) w1 = *(const bf16x4*)(th + (size_t)n1*32 + l8*4);
    #pragma unroll
    for (int j=0;j<4;j++) a4[j] += bf2f((unsigned short)u0[j]) + bf2f((unsigned short)u1[j]);
    c0 = c2; c1 = c3; u0 = u2; u1 = u3;
    c2 = n0; c3 = n1; u2 = w0; u3 = w1;
    i += 16;
  }
  #pragma unroll
  for (int j=0;j<4;j++){
    a4[j] += __shfl_down(a4[j], 32);
    a4[j] += __shfl_down(a4[j], 16);
    a4[j] += __shfl_down(a4[j], 8);
  }
  if (lane < 8){
    float ndr = nd[row];
    int half = l8>>2, c0x = (l8&3)*4;
    float4 r;
    r.x = a4[0]*ndr + b3[c0x+0];
    r.y = a4[1]*ndr + b3[c0x+1];
    r.z = a4[2]*ndr + b3[c0x+2];
    r.w = a4[3]*ndr + b3[c0x+3];
    if (half==0) *(float4*)&hout[(size_t)row*16 + c0x] = r;
    int hb = half*16 + c0x;
    hbuf[wave][hb+0]=r.x; hbuf[wave][hb+1]=r.y; hbuf[wave][hb+2]=r.z; hbuf[wave][hb+3]=r.w;
  }
  if (lane < 16){
    int d = lane;
    float e1v = fmaxf(hbuf[wave][d],    0.f);
    float e2v = fmaxf(hbuf[wave][16+d], 0.f);
    float s1 = e1v*e1v, s2 = e2v*e2v;
    #pragma unroll
    for (int off=1; off<16; off<<=1){
      s1 += __shfl_xor(s1, off);
      s2 += __shfl_xor(s2, off);
    }
    float r1 = 1.0f/fmaxf(sqrtf(s1),1e-12f);
    float r2 = 1.0f/fmaxf(sqrtf(s2),1e-12f);
    gbuf[wave][d]    = sigm(e1v*r1);
    gbuf[wave][16+d] = sigm(e2v*r2);
    float vh1=0.f, vh2=0.f;
    #pragma unroll
    for (int e2i=0;e2i<16;e2i++){
      float w = Ws[d*16+e2i];
      vh1 += w*gbuf[wave][e2i];
      vh2 += w*gbuf[wave][16+e2i];
    }
    float q00 = e1v*vh1, q01 = e2v*vh1, q10 = e2v*vh2, q11 = e1v*vh2;
    #pragma unroll
    for (int off=1; off<16; off<<=1){
      q00 += __shfl_xor(q00, off);
      q01 += __shfl_xor(q01, off);
      q10 += __shfl_xor(q10, off);
      q11 += __shfl_xor(q11, off);
    }
    if (lane==0){
      float bb = bdh[0];
      rh [(size_t)row*2+0]=q00+bb; rh [(size_t)row*2+1]=q01+bb;
      rha[(size_t)row*2+0]=q10+bb; rha[(size_t)row*2+1]=q11+bb;
    }
  }
}

// ---------------- launch ----------------
extern "C" void kernel_launch(void* const* d_in, const int* in_sizes, int n_in,
                              void* d_out, int out_size, void* d_ws, size_t ws_size,
                              hipStream_t stream){
  const float* x   = (const float*)d_in[0];
  const float* W1  = (const float*)d_in[1];
  const float* b1  = (const float*)d_in[2];
  const float* W2  = (const float*)d_in[3];
  const float* b2  = (const float*)d_in[4];
  const float* W3  = (const float*)d_in[5];
  const float* b3  = (const float*)d_in[6];
  const float* Wdo = (const float*)d_in[7];
  const float* bdo = (const float*)d_in[8];
  const float* Wdh = (const float*)d_in[9];
  const float* bdh = (const float*)d_in[10];
  const int* ei    = (const int*)d_in[11];
  const int* perm  = (const int*)d_in[12];
  const int* esrc = ei;
  const int* edst = ei + EE;

  char* ws = (char*)d_ws;
  size_t off = 0;
  auto alloc = [&](size_t bytes)->void*{ void* p = ws + off; off += (bytes + 255) & ~(size_t)255; return p; };
  unsigned short* z  = (unsigned short*)alloc((size_t)NN*256*2);
  unsigned short* ob = (unsigned short*)alloc((size_t)2*NN*128*2);
  unsigned short* tz = (unsigned short*)alloc((size_t)NN*128*2);
  unsigned short* th = (unsigned short*)alloc((size_t)NN*32*2);
  int* deg = (int*)alloc((size_t)2*NN*4);
  int* dout_ = deg; int* din_ = deg + NN;
  float* ns = (float*)alloc((size_t)NN*4);
  float* nd = (float*)alloc((size_t)NN*4);
  int* inv  = (int*)alloc((size_t)NN*4);
  float* rn = (float*)alloc((size_t)2*NN*4);
  int* cursor = (int*)alloc((size_t)NN*4);
  int* row_ptr = (int*)alloc((size_t)(NN+1)*4);
  int2* colx2 = (int2*)alloc((size_t)EE*8);
  int* chunk = (int*)alloc((size_t)NN*4);
  int* bsum = (int*)alloc((size_t)SCB*4);
  int* bpre = (int*)alloc((size_t)SCB*4);
  unsigned short* W1T = (unsigned short*)alloc((size_t)1024*128*2);
  unsigned short* W2T = (unsigned short*)alloc((size_t)128*128*2);
  unsigned short* WdoB = (unsigned short*)alloc((size_t)128*128*2);
  unsigned short* W3c = (unsigned short*)alloc((size_t)16*128*2);

  float* out_h   = (float*)d_out;
  float* out_ro  = out_h  + (size_t)NN*16;
  float* out_rh  = out_ro + (size_t)NN*2;
  float* out_roa = out_rh + (size_t)NN*2;
  float* out_rha = out_roa+ (size_t)NN*2;

  hipMemsetAsync(deg, 0, (size_t)2*NN*4, stream);
  k_wcvt<<<648, 256, 0, stream>>>(W1, W2, Wdo, W3, W1T, W2T, WdoB, W3c);
  // GC1 GEMM half 1 + degree counting, overlapped
  k_g1<0><<<NG1 + FB, 512, 0, stream>>>(x, W1T, tz, esrc, edst, dout_, din_,
                                        nullptr, perm, 0);
  k_scan1<<<SCB, 1024, 0, stream>>>(din_, chunk, bsum);
  k_scan2<<<1, 128, 0, stream>>>(bsum, bpre, row_ptr);
  k_scan3<<<(NN+255)/256, 256, 0, stream>>>(din_, chunk, bpre, dout_, perm, row_ptr, cursor, ns, nd, inv);
  // GC1 GEMM half 2 + CSR fill, overlapped
  k_g1<1><<<NG1 + FB, 512, 0, stream>>>(x, W1T, tz, esrc, edst, cursor, nullptr,
                                        colx2, perm, NG1);

  int gb2 = (2*NN)/64;
  // GC1 aggregation: both encodes via folded perm-gather from t
  k_agg1<<<(NN+3)/4,256,0,stream>>>(tz, ns, row_ptr, colx2, nd, b1, ob);
  // GC2 fused over both encodes, +residual agg (fuses rn)
  k_gemmA<128,0,1><<<gb2,256,0,stream>>>(ob, W2T, z, ns, nullptr, 2*NN,
                                         nullptr, nullptr, nullptr, nullptr, nullptr);
  k_agg128<<<(NN+3)/4,256,0,stream>>>(z, row_ptr, colx2, nd, b2, ob, rn);
  // disc GEMM + fused GC3-mult (th) + fused ret_o epilogue
  k_gemmA<128,1,3><<<gb2,256,0,stream>>>(ob, WdoB, nullptr, bdo, rn, 2*NN,
                                         out_ro, out_roa, W3c, ns, th);
  // GC3 agg + fused ret_h
  k_agg16<<<(NN+3)/4,256,0,stream>>>(th, row_ptr, colx2, nd, b3, Wdh, bdh, out_h, out_rh, out_rha);
}

// Round 19
// 637.300 us; speedup vs baseline: 1.1793x; 1.0198x over previous
//
#include <hip/hip_runtime.h>
#include <math.h>

#define NN 100000
#define EE 1600000
#define SCB 98    // ceil(NN/1024)
#define NG1 391   // GEMM blocks per half (2*391*128 >= NN)
#define FB 3125   // ceil(EE/512)
#define WXB 68    // small-weight-convert tail blocks (68*512 = 34816)

typedef __attribute__((ext_vector_type(8))) short bf16x8;
typedef __attribute__((ext_vector_type(4))) short bf16x4;
typedef __attribute__((ext_vector_type(4))) float f32x4;

__device__ __forceinline__ unsigned short f2bf(float x){
  union { float f; unsigned u; } v; v.f = x;
  unsigned r = v.u + 0x7FFFu + ((v.u >> 16) & 1u);
  return (unsigned short)(r >> 16);
}
__device__ __forceinline__ float bf2f(unsigned short h){
  union { unsigned u; float f; } v; v.u = ((unsigned)h) << 16; return v.f;
}
__device__ __forceinline__ float sigm(float x){ return 1.0f/(1.0f+__expf(-x)); }

// light barrier: ds-ops drained, global loads stay in flight (T3/T4; guide §5)
__device__ __forceinline__ void barrier_lds_only(){
  asm volatile("s_waitcnt lgkmcnt(0)" ::: "memory");
  __builtin_amdgcn_s_barrier();
  __builtin_amdgcn_sched_barrier(0);
}

// ---------------- W1 convert + deg zeroing (one launch) ----------------
__global__ __launch_bounds__(256) void k_wcvt_mem(const float* __restrict__ W1,
                      unsigned short* __restrict__ W1T, int* __restrict__ deg){
  int b = blockIdx.x;
  if (b < 512){
    int i = b*256 + threadIdx.x;   // < 131072
    int c = i>>13, r = i&8191, col = r>>6, k = c*64 + (r&63);
    W1T[i] = f2bf(W1[(size_t)k*128 + col]);
  } else {
    int j = (b-512)*256 + threadIdx.x;
    if (j < 50000) ((int4*)deg)[j] = make_int4(0,0,0,0);
  }
}

// ---------------- scan phase 1 ----------------
__global__ __launch_bounds__(1024) void k_scan1(const int* __restrict__ din, int* __restrict__ chunk,
                        int* __restrict__ bsum){
  __shared__ int wsum[16];
  int t = threadIdx.x, lane = t & 63, w = t >> 6;
  int i = blockIdx.x*1024 + t;
  int v = (i < NN) ? din[i] : 0;
  int x = v;
  #pragma unroll
  for (int off=1; off<64; off<<=1){
    int y = __shfl_up(x, off);
    if (lane>=off) x += y;
  }
  if (lane==63) wsum[w] = x;
  __syncthreads();
  int pre = 0;
  #pragma unroll
  for (int j=0;j<16;j++) if (j<w) pre += wsum[j];
  int incl = x + pre;
  if (i < NN) chunk[i] = incl;
  if (t == 1023) bsum[blockIdx.x] = incl;
}

// ---------------- scan phase 2+3 fused: per-block local prefix of bsum ----------------
__global__ __launch_bounds__(256) void k_scan3b(const int* __restrict__ din, const int* __restrict__ chunk,
                       const int* __restrict__ bsum, const int* __restrict__ dout,
                       int* __restrict__ row_ptr, int* __restrict__ cursor,
                       float* __restrict__ ns, float* __restrict__ nd){
  __shared__ int bs[SCB];
  int t = threadIdx.x;
  if (t < SCB) bs[t] = bsum[t];
  __syncthreads();
  int i = blockIdx.x*256 + t;
  if (i < NN){
    int ci = i>>10;
    int pre = 0;
    for (int j=0;j<ci;j++) pre += bs[j];
    int d = din[i];
    int val = chunk[i] + pre;
    row_ptr[i+1] = val;
    cursor[i] = val - d;
    ns[i] = rsqrtf((float)max(dout[i],1));
    nd[i] = rsqrtf((float)max(d,1));
    if (i == 0) row_ptr[0] = 0;
  }
}

// ---------------- GC1 GEMM half + tail jobs (heterogeneous grid) ----------------
// TAIL=0: tails = degree counting + small-weight conversion; TAIL=1: tails = CSR fill
// (colx2[pos] = {src, perm[src]}). GEMM blocks write raw t (no ns/inv dep).
template<int TAIL>
__global__ __launch_bounds__(512,4) void k_g1(
    const float* __restrict__ A, const unsigned short* __restrict__ Wc,
    unsigned short* __restrict__ tz,
    const int* __restrict__ src, const int* __restrict__ dst,
    int* __restrict__ p0, int* __restrict__ p1,
    int2* __restrict__ colx2, const int* __restrict__ perm, int rowBase,
    unsigned short* __restrict__ W2T, unsigned short* __restrict__ WdoB,
    unsigned short* __restrict__ W3c,
    const float* __restrict__ W2f, const float* __restrict__ Wdof,
    const float* __restrict__ W3f)
{
  constexpr int NC = 16;
  __shared__ __align__(16) unsigned short As[2*128*72];
  __shared__ __align__(16) unsigned short Bs[2*128*64];
  if constexpr (TAIL==0){
    if (blockIdx.x >= NG1 + FB){
      int i2 = (blockIdx.x - NG1 - FB)*512 + threadIdx.x;
      if (i2 < 16384){
        int c = i2>>13, r = i2&8191, col = r>>6, k = c*64 + (r&63);
        W2T[i2] = f2bf(W2f[(size_t)k*128 + col]);
      } else if (i2 < 32768){
        int j = i2-16384;
        int c = j>>13, r = j&8191, col = r>>6, k = c*64 + (r&63);
        WdoB[j] = f2bf(Wdof[(size_t)col*128 + k]);   // B = Wdo^T
      } else if (i2 < 34816){
        int j = i2-32768;
        int col = j>>7, k = j&127;
        W3c[j] = f2bf(W3f[(size_t)k*16 + col]);
      }
      return;
    }
  }
  if (blockIdx.x >= NG1){
    int e = (blockIdx.x - NG1)*512 + threadIdx.x;
    if (e < EE){
      if constexpr (TAIL==0){
        atomicAdd(&p0[src[e]],1);
        atomicAdd(&p1[dst[e]],1);
      } else {
        int s = src[e];
        int pos = atomicAdd(&p0[dst[e]],1);
        colx2[pos] = make_int2(s, perm[s]);
      }
    }
    return;
  }
  int t = threadIdx.x, wave = t>>6, lane = t&63;
  int row0 = (rowBase + blockIdx.x)*128;

  int srow = t>>4;
  int scol4 = (t&15)*4;
  int colB = t>>2;
  int s0B = (t&3)*2;

  f32x4 acc[8] = {};
  float4 S0[4], S1[4];
  bf16x8 w0{}, w1{};

#define ALOAD(SET, CC) { \
  _Pragma("unroll") \
  for (int p=0;p<4;p++){ \
    int rr = min(row0 + p*32 + srow, NN-1); \
    SET[p] = *(const float4*)(A + (size_t)rr*1024 + (CC)*64 + scol4); } }

#define AWRITE(SET, BUF) { \
  _Pragma("unroll") \
  for (int p=0;p<4;p++){ \
    short4 s4; \
    s4.x = (short)f2bf(SET[p].x); s4.y = (short)f2bf(SET[p].y); \
    s4.z = (short)f2bf(SET[p].z); s4.w = (short)f2bf(SET[p].w); \
    *(short4*)&As[(BUF)*9216 + (p*32+srow)*72 + scol4] = s4; } }

#define BLOAD(CC) { \
  const unsigned short* gp = Wc + (size_t)(CC)*8192 + (size_t)t*16; \
  w0 = *(const bf16x8*)(gp); \
  w1 = *(const bf16x8*)(gp+8); }

#define BWRITE(BUF) { \
  unsigned short* bb = &Bs[(BUF)*8192]; \
  *(bf16x8*)&bb[colB*64 + ((s0B     ^ (colB&7))<<3)] = w0; \
  *(bf16x8*)&bb[colB*64 + (((s0B+1) ^ (colB&7))<<3)] = w1; }

  ALOAD(S0, 0);
  BLOAD(0);
  AWRITE(S0, 0);
  BWRITE(0);
  ALOAD(S1, 1);
  BLOAD(1);
  barrier_lds_only();

  int slot0 = lane>>4;
  int c = lane & 15;
  int arow = wave*16 + (lane&15);
  #pragma unroll
  for (int cc=0; cc<NC; ++cc){
    if (cc+2 < NC){
      if (cc&1) { ALOAD(S1, cc+2); } else { ALOAD(S0, cc+2); }
    }
    int cur = cc&1;
    const unsigned short* ab = &As[cur*9216];
    const unsigned short* bb = &Bs[cur*8192];
    {
      bf16x8 af = *(const bf16x8*)&ab[arow*72 + (slot0<<3)];
      #pragma unroll
      for (int j=0;j<8;j++){
        int cj = j*16 + c;
        bf16x8 b = *(const bf16x8*)&bb[cj*64 + ((slot0 ^ (cj&7))<<3)];
        acc[j] = __builtin_amdgcn_mfma_f32_16x16x32_bf16(af, b, acc[j], 0, 0, 0);
      }
    }
    {
      bf16x8 af = *(const bf16x8*)&ab[arow*72 + 32 + (slot0<<3)];
      #pragma unroll
      for (int j=0;j<8;j++){
        int cj = j*16 + c;
        bf16x8 b = *(const bf16x8*)&bb[cj*64 + (((slot0+4) ^ (cj&7))<<3)];
        acc[j] = __builtin_amdgcn_mfma_f32_16x16x32_bf16(af, b, acc[j], 0, 0, 0);
      }
    }
    if (cc+1 < NC){
      int nb = (cc+1)&1;
      if (cc&1) { AWRITE(S0, nb); } else { AWRITE(S1, nb); }
      BWRITE(nb);
      barrier_lds_only();
      if (cc+2 < NC) BLOAD(cc+2);
    }
  }
#undef ALOAD
#undef AWRITE
#undef BLOAD
#undef BWRITE

  // epilogue: coalesced write of raw GEMM output (no scale, no scatter)
  int rbase = row0 + wave*16 + (lane>>4)*4;
  #pragma unroll
  for (int j=0;j<8;j++){
    int colx = j*16 + c;
    #pragma unroll
    for (int r=0;r<4;r++){
      int row = rbase + r;
      if (row < NN) tz[(size_t)row*128 + colx] = f2bf(acc[j][r]);
    }
  }
}

// ---------------- GC1 aggregation from t/colx2/ns (both encodes) ----------------
__global__ __launch_bounds__(256) void k_agg1(
  const unsigned short* __restrict__ tz,
  const float* __restrict__ ns,
  const int* __restrict__ row_ptr, const int2* __restrict__ colx2,
  const float* __restrict__ nd, const float* __restrict__ bias,
  unsigned short* __restrict__ ob)
{
  int wave = threadIdx.x>>6, lane = threadIdx.x&63;
  int row = blockIdx.x*4 + wave;
  if (row >= NN) return;
  int s = row_ptr[row], e = row_ptr[row+1];
  int es = lane>>5;
  int half = (lane>>4)&1;
  int c8 = (lane&15)*8;
  float acc[8] = {};
  bf16x8 zer = {};
  int i = s + es;

#define FETCH1(IDX, U, F) { \
  if ((IDX) < e){ \
    int2 cc = colx2[(IDX)]; \
    int rr = half ? cc.y : cc.x; \
    F = ns[cc.x]; \
    U = *(const bf16x8*)(tz + (size_t)rr*128 + c8); \
  } else { F = 0.0f; U = zer; } }

  bf16x8 u0, u1, u2, u3;
  float f0, f1, f2, f3;
  FETCH1(i,   u0, f0);
  FETCH1(i+2, u1, f1);
  FETCH1(i+4, u2, f2);
  FETCH1(i+6, u3, f3);
  while (i < e){
    bf16x8 w0, w1; float g0, g1;
    FETCH1(i+8,  w0, g0);
    FETCH1(i+10, w1, g1);
    #pragma unroll
    for (int j=0;j<8;j++)
      acc[j] += bf2f((unsigned short)u0[j])*f0 + bf2f((unsigned short)u1[j])*f1;
    u0=u2; f0=f2; u1=u3; f1=f3;
    u2=w0; f2=g0; u3=w1; f3=g1;
    i += 4;
  }
#undef FETCH1
  #pragma unroll
  for (int j=0;j<8;j++) acc[j] += __shfl_down(acc[j], 32);
  if (lane < 32){
    float ndr = nd[row];
    size_t oof = half ? (size_t)(NN+row)*128 + c8 : (size_t)row*128 + c8;
    bf16x8 wv;
    #pragma unroll
    for (int j=0;j<8;j++) wv[j] = (short)f2bf(acc[j]*ndr + bias[c8+j]);
    *(bf16x8*)(ob + oof) = wv;
  }
}

// ---------------- A-fragment holder (bf16 direct) ----------------
struct ARU { bf16x8 a; };
__device__ __forceinline__ void aload(ARU& r, const unsigned short* p){
  r.a = *(const bf16x8*)p;
}
template<int IM>
__device__ __forceinline__ bf16x8 aconv(const ARU& r, float rs){
  if constexpr (IM==0) return r.a;
  else {
    bf16x8 o;
    #pragma unroll
    for (int i=0;i<8;i++){
      float v = sigm(fmaxf(bf2f((unsigned short)r.a[i]),0.0f)*rs);
      o[i] = (short)f2bf(v);
    }
    return o;
  }
}
__device__ __forceinline__ bf16x8 araw(const ARU& r){ return r.a; }

// ---------------- small-K MFMA GEMM (bf16 A direct) ----------------
template<int KDIM, int IN_MODE, int OUT_MODE>
__global__ __launch_bounds__(256,2) void k_gemmA(
    const unsigned short* __restrict__ A, const unsigned short* __restrict__ Wc,
    unsigned short* __restrict__ out0,
    const float* __restrict__ scale,
    const float* __restrict__ rn, int nrows,
    float* __restrict__ ro, float* __restrict__ roa,
    const unsigned short* __restrict__ W3c, const float* __restrict__ ns2,
    unsigned short* __restrict__ th)
{
  constexpr int NC = KDIM/64;
  __shared__ __align__(16) unsigned short Bs[2*128*64];
  __shared__ __align__(16) unsigned short W3s[OUT_MODE==3 ? 16*128 : 16];
  int t = threadIdx.x, wave = t>>6, lane = t&63;
  int row0 = blockIdx.x*64;
  int arow = row0 + wave*16 + (lane&15);
  int kof = (lane>>4)*8;
  int arow_c = min(arow, nrows-1);
  const unsigned short* ap = A + (size_t)arow_c*KDIM + kof;
  float rscale = 1.0f;
  if constexpr (IN_MODE==1) rscale = rn[arow_c];

  int scol = t>>3;
  int sw = ((t&7) ^ (scol&7))<<3;

  unsigned short* b0 = &Bs[0];
  unsigned short* b1 = &Bs[128*64];
  const unsigned short* bcur = b0; unsigned short* bnxt = b1;

  f32x4 acc[8] = {};
  f32x4 acc2 = {};
  ARU A0a{},A0b{},A1a{},A1b{},A2a{},A2b{};
  bf16x8 w0{},w1{},w2{},w3{};

  {
    const unsigned short* gp = Wc + (size_t)t*8;
    bf16x8 t0 = *(const bf16x8*)(gp);
    bf16x8 t1 = *(const bf16x8*)(gp+2048);
    bf16x8 t2 = *(const bf16x8*)(gp+4096);
    bf16x8 t3 = *(const bf16x8*)(gp+6144);
    *(bf16x8*)&b0[(0*32+scol)*64 + sw] = t0;
    *(bf16x8*)&b0[(1*32+scol)*64 + sw] = t1;
    *(bf16x8*)&b0[(2*32+scol)*64 + sw] = t2;
    *(bf16x8*)&b0[(3*32+scol)*64 + sw] = t3;
  }
  if constexpr (OUT_MODE==3){
    int wc = t>>4, wsl = t&15;
    bf16x8 v = *(const bf16x8*)(W3c + wc*128 + wsl*8);
    *(bf16x8*)&W3s[wc*128 + ((wsl ^ (wc&7))<<3)] = v;
  }
  aload(A0a, ap); aload(A0b, ap+32);
  if (NC>1){
    const unsigned short* gp = Wc + 8192 + (size_t)t*8;
    w0 = *(const bf16x8*)(gp);
    w1 = *(const bf16x8*)(gp+2048);
    w2 = *(const bf16x8*)(gp+4096);
    w3 = *(const bf16x8*)(gp+6144);
    aload(A1a, ap+64); aload(A1b, ap+96);
  }
  __syncthreads();

  int slot0 = lane>>4;
  int c = lane & 15;
  #pragma unroll
  for (int cc=0; cc<NC; ++cc){
    if (cc+2 < NC){
      aload(A2a, ap + (cc+2)*64);
      aload(A2b, ap + (cc+2)*64 + 32);
    }
    {
      bf16x8 af = aconv<IN_MODE>(A0a, rscale);
      #pragma unroll
      for (int j=0;j<8;j++){
        int cj = j*16 + c;
        bf16x8 b = *(const bf16x8*)&bcur[cj*64 + ((slot0 ^ (cj&7))<<3)];
        acc[j] = __builtin_amdgcn_mfma_f32_16x16x32_bf16(af, b, acc[j], 0, 0, 0);
      }
      if constexpr (OUT_MODE==3){
        int sl = cc*8 + slot0;
        bf16x8 b = *(const bf16x8*)&W3s[c*128 + ((sl ^ (c&7))<<3)];
        acc2 = __builtin_amdgcn_mfma_f32_16x16x32_bf16(araw(A0a), b, acc2, 0, 0, 0);
      }
    }
    {
      bf16x8 af = aconv<IN_MODE>(A0b, rscale);
      #pragma unroll
      for (int j=0;j<8;j++){
        int cj = j*16 + c;
        bf16x8 b = *(const bf16x8*)&bcur[cj*64 + (((slot0+4) ^ (cj&7))<<3)];
        acc[j] = __builtin_amdgcn_mfma_f32_16x16x32_bf16(af, b, acc[j], 0, 0, 0);
      }
      if constexpr (OUT_MODE==3){
        int sl = cc*8 + 4 + slot0;
        bf16x8 b = *(const bf16x8*)&W3s[c*128 + ((sl ^ (c&7))<<3)];
        acc2 = __builtin_amdgcn_mfma_f32_16x16x32_bf16(araw(A0b), b, acc2, 0, 0, 0);
      }
    }
    if (cc+1 < NC){
      *(bf16x8*)&bnxt[(0*32+scol)*64 + sw] = w0;
      *(bf16x8*)&bnxt[(1*32+scol)*64 + sw] = w1;
      *(bf16x8*)&bnxt[(2*32+scol)*64 + sw] = w2;
      *(bf16x8*)&bnxt[(3*32+scol)*64 + sw] = w3;
      barrier_lds_only();
      const unsigned short* tmp = bcur; bcur = bnxt; bnxt = (unsigned short*)tmp;
      if (cc+2 < NC){
        const unsigned short* gp = Wc + (size_t)(cc+2)*8192 + (size_t)t*8;
        w0 = *(const bf16x8*)(gp);
        w1 = *(const bf16x8*)(gp+2048);
        w2 = *(const bf16x8*)(gp+4096);
        w3 = *(const bf16x8*)(gp+6144);
      }
    }
    A0a=A1a; A0b=A1b; A1a=A2a; A1b=A2b;
  }

  if constexpr (OUT_MODE==3){
    #pragma unroll
    for (int r=0;r<4;r++){
      int row = row0 + wave*16 + (lane>>4)*4 + r;
      int sidx = row>=NN ? row-NN : row;
      float v = acc2[r]*ns2[sidx];
      size_t tof = row<NN ? (size_t)row*32 + c : (size_t)(row-NN)*32 + 16 + c;
      th[tof] = f2bf(v);
    }
    __syncthreads();
    unsigned short* Os = &Bs[0];
    unsigned short* Oo = &Bs[8192];
    for (int p=t; p<2048; p+=256){
      int r = (p>>4)&63, seg = p&15;
      int row = row0 + r;
      int srcrow = (p<1024) ? row : (row<NN ? row+NN : row-NN);
      unsigned short* dst = (p<1024) ? Os : Oo;
      *(bf16x8*)&dst[r*128 + ((seg ^ (r&7))<<3)] = *(const bf16x8*)&A[(size_t)srcrow*128 + seg*8];
    }
    __syncthreads();
    float bb = scale[0];
    #pragma unroll
    for (int r=0;r<4;r++){
      int lr = wave*16 + (lane>>4)*4 + r;
      float dsame=0.f, doth=0.f;
      #pragma unroll
      for (int j=0;j<8;j++){
        float v = acc[j][r];
        int colj = j*16 + c;
        int idx = lr*128 + (((colj>>3) ^ (lr&7))<<3) + (colj&7);
        dsame += fmaxf(bf2f(Os[idx]),0.f)*v;
        doth  += fmaxf(bf2f(Oo[idx]),0.f)*v;
      }
      #pragma unroll
      for (int off=1; off<16; off<<=1){
        dsame += __shfl_xor(dsame, off);
        doth  += __shfl_xor(doth, off);
      }
      if (c==0){
        int row = row0 + lr;
        if (row < NN){
          ro[(size_t)row*2+0] = dsame + bb;
          ro[(size_t)row*2+1] = doth + bb;
        } else {
          int m = row - NN;
          roa[(size_t)m*2+0] = dsame + bb;
          roa[(size_t)m*2+1] = doth + bb;
        }
      }
    }
  } else {
    int rbase = row0 + wave*16 + (lane>>4)*4;
    #pragma unroll
    for (int j=0;j<8;j++){
      int colx = j*16 + c;
      #pragma unroll
      for (int r=0;r<4;r++){
        int row = rbase + r;
        if (row < nrows){
          float v = acc[j][r];
          int sidx = row >= NN ? row - NN : row;
          size_t zof = row < NN ? (size_t)row*256 + colx : (size_t)(row-NN)*256 + 128 + colx;
          out0[zof] = f2bf(v * scale[sidx]);
        }
      }
    }
  }
}

// ---------------- CSR aggregation (GC2, residual), interleaved z[N][2][128] ----------------
__global__ __launch_bounds__(256) void k_agg128(
  const unsigned short* __restrict__ z,
  const int* __restrict__ row_ptr, const int2* __restrict__ colx2,
  const float* __restrict__ nd, const float* __restrict__ bias,
  unsigned short* __restrict__ ob, float* __restrict__ rn)
{
  int wave = threadIdx.x>>6, lane = threadIdx.x&63;
  int row = blockIdx.x*4 + wave;
  if (row >= NN) return;
  int s = row_ptr[row], e = row_ptr[row+1];
  int es = lane>>5;
  int half = (lane>>4)&1;
  int c8 = (lane&15)*8;
  size_t lof = (size_t)half*128 + c8;
  float acc[8] = {};
  int i = s + es;
  int c0 = (i   < e) ? colx2[i].x   : -1;
  int c1 = (i+2 < e) ? colx2[i+2].x : -1;
  int c2 = (i+4 < e) ? colx2[i+4].x : -1;
  int c3 = (i+6 < e) ? colx2[i+6].x : -1;
  bf16x8 u0 = {}, u1 = {}, u2 = {}, u3 = {};
  if (c0 >= 0) u0 = *(const bf16x8*)(z + (size_t)c0*256 + lof);
  if (c1 >= 0) u1 = *(const bf16x8*)(z + (size_t)c1*256 + lof);
  if (c2 >= 0) u2 = *(const bf16x8*)(z + (size_t)c2*256 + lof);
  if (c3 >= 0) u3 = *(const bf16x8*)(z + (size_t)c3*256 + lof);
  while (c0 >= 0){
    int n0 = (i+8  < e) ? colx2[i+8].x  : -1;
    int n1 = (i+10 < e) ? colx2[i+10].x : -1;
    bf16x8 w0 = {}, w1 = {};
    if (n0 >= 0) w0 = *(const bf16x8*)(z + (size_t)n0*256 + lof);
    if (n1 >= 0) w1 = *(const bf16x8*)(z + (size_t)n1*256 + lof);
    #pragma unroll
    for (int j=0;j<8;j++) acc[j] += bf2f((unsigned short)u0[j]) + bf2f((unsigned short)u1[j]);
    c0 = c2; c1 = c3; u0 = u2; u1 = u3;
    c2 = n0; c3 = n1; u2 = w0; u3 = w1;
    i += 4;
  }
  #pragma unroll
  for (int j=0;j<8;j++) acc[j] += __shfl_down(acc[j], 32);
  if (lane < 32){
    float ndr = nd[row];
    size_t oof = half ? (size_t)(NN+row)*128 + c8 : (size_t)row*128 + c8;
    float ra[8];
    #pragma unroll
    for (int j=0;j<8;j++) ra[j] = acc[j]*ndr + bias[c8+j];
    {
      bf16x8 pv = *(const bf16x8*)(ob + oof);
      #pragma unroll
      for (int j=0;j<8;j++) ra[j] += bf2f((unsigned short)pv[j]);
    }
    bf16x8 wv;
    #pragma unroll
    for (int j=0;j<8;j++) wv[j] = (short)f2bf(ra[j]);
    *(bf16x8*)(ob + oof) = wv;
    {
      float sa = 0.f;
      #pragma unroll
      for (int j=0;j<8;j++){ float x1 = fmaxf(ra[j],0.f); sa += x1*x1; }
      sa += __shfl_down(sa, 8);
      sa += __shfl_down(sa, 4);
      sa += __shfl_down(sa, 2);
      sa += __shfl_down(sa, 1);
      if ((lane&15)==0) rn[half ? NN+row : row] = 1.0f/fmaxf(sqrtf(sa),1e-12f);
    }
  }
}

// ---------------- width-16 aggregation (GC3) + fused ret_h ----------------
__global__ __launch_bounds__(256) void k_agg16(
  const unsigned short* __restrict__ th,
  const int* __restrict__ row_ptr, const int2* __restrict__ colx2,
  const float* __restrict__ nd, const float* __restrict__ b3,
  const float* __restrict__ Wdh, const float* __restrict__ bdh,
  float* __restrict__ hout, float* __restrict__ rh, float* __restrict__ rha)
{
  __shared__ float Ws[256];
  __shared__ float hbuf[4][32];
  __shared__ float gbuf[4][32];
  int t = threadIdx.x;
  Ws[t] = Wdh[t];
  __syncthreads();
  int wave = t>>6, lane = t&63;
  int row = blockIdx.x*4 + wave;
  if (row >= NN) return;
  int s = row_ptr[row], e = row_ptr[row+1];
  int es = lane>>3, l8 = lane&7;
  float a4[4] = {};
  int i = s + es;
  int c0 = (i   <e)? colx2[i].x    : -1;
  int c1 = (i+8 <e)? colx2[i+8].x  : -1;
  int c2 = (i+16<e)? colx2[i+16].x : -1;
  int c3 = (i+24<e)? colx2[i+24].x : -1;
  bf16x4 u0 = {}, u1 = {}, u2 = {}, u3 = {};
  if (c0 >= 0) u0 = *(const bf16x4*)(th + (size_t)c0*32 + l8*4);
  if (c1 >= 0) u1 = *(const bf16x4*)(th + (size_t)c1*32 + l8*4);
  if (c2 >= 0) u2 = *(const bf16x4*)(th + (size_t)c2*32 + l8*4);
  if (c3 >= 0) u3 = *(const bf16x4*)(th + (size_t)c3*32 + l8*4);
  while (c0 >= 0){
    int n0 = (i+32<e)? colx2[i+32].x : -1;
    int n1 = (i+40<e)? colx2[i+40].x : -1;
    bf16x4 w0 = {}, w1 = {};
    if (n0 >= 0) w0 = *(const bf16x4*)(th + (size_t)n0*32 + l8*4);
    if (n1 >= 0) w1 = *(const bf16x4*)(th + (size_t)n1*32 + l8*4);
    #pragma unroll
    for (int j=0;j<4;j++) a4[j] += bf2f((unsigned short)u0[j]) + bf2f((unsigned short)u1[j]);
    c0 = c2; c1 = c3; u0 = u2; u1 = u3;
    c2 = n0; c3 = n1; u2 = w0; u3 = w1;
    i += 16;
  }
  #pragma unroll
  for (int j=0;j<4;j++){
    a4[j] += __shfl_down(a4[j], 32);
    a4[j] += __shfl_down(a4[j], 16);
    a4[j] += __shfl_down(a4[j], 8);
  }
  if (lane < 8){
    float ndr = nd[row];
    int half = l8>>2, c0x = (l8&3)*4;
    float4 r;
    r.x = a4[0]*ndr + b3[c0x+0];
    r.y = a4[1]*ndr + b3[c0x+1];
    r.z = a4[2]*ndr + b3[c0x+2];
    r.w = a4[3]*ndr + b3[c0x+3];
    if (half==0) *(float4*)&hout[(size_t)row*16 + c0x] = r;
    int hb = half*16 + c0x;
    hbuf[wave][hb+0]=r.x; hbuf[wave][hb+1]=r.y; hbuf[wave][hb+2]=r.z; hbuf[wave][hb+3]=r.w;
  }
  if (lane < 16){
    int d = lane;
    float e1v = fmaxf(hbuf[wave][d],    0.f);
    float e2v = fmaxf(hbuf[wave][16+d], 0.f);
    float s1 = e1v*e1v, s2 = e2v*e2v;
    #pragma unroll
    for (int off=1; off<16; off<<=1){
      s1 += __shfl_xor(s1, off);
      s2 += __shfl_xor(s2, off);
    }
    float r1 = 1.0f/fmaxf(sqrtf(s1),1e-12f);
    float r2 = 1.0f/fmaxf(sqrtf(s2),1e-12f);
    gbuf[wave][d]    = sigm(e1v*r1);
    gbuf[wave][16+d] = sigm(e2v*r2);
    float vh1=0.f, vh2=0.f;
    #pragma unroll
    for (int e2i=0;e2i<16;e2i++){
      float w = Ws[d*16+e2i];
      vh1 += w*gbuf[wave][e2i];
      vh2 += w*gbuf[wave][16+e2i];
    }
    float q00 = e1v*vh1, q01 = e2v*vh1, q10 = e2v*vh2, q11 = e1v*vh2;
    #pragma unroll
    for (int off=1; off<16; off<<=1){
      q00 += __shfl_xor(q00, off);
      q01 += __shfl_xor(q01, off);
      q10 += __shfl_xor(q10, off);
      q11 += __shfl_xor(q11, off);
    }
    if (lane==0){
      float bb = bdh[0];
      rh [(size_t)row*2+0]=q00+bb; rh [(size_t)row*2+1]=q01+bb;
      rha[(size_t)row*2+0]=q10+bb; rha[(size_t)row*2+1]=q11+bb;
    }
  }
}

// ---------------- launch ----------------
extern "C" void kernel_launch(void* const* d_in, const int* in_sizes, int n_in,
                              void* d_out, int out_size, void* d_ws, size_t ws_size,
                              hipStream_t stream){
  const float* x   = (const float*)d_in[0];
  const float* W1  = (const float*)d_in[1];
  const float* b1  = (const float*)d_in[2];
  const float* W2  = (const float*)d_in[3];
  const float* b2  = (const float*)d_in[4];
  const float* W3  = (const float*)d_in[5];
  const float* b3  = (const float*)d_in[6];
  const float* Wdo = (const float*)d_in[7];
  const float* bdo = (const float*)d_in[8];
  const float* Wdh = (const float*)d_in[9];
  const float* bdh = (const float*)d_in[10];
  const int* ei    = (const int*)d_in[11];
  const int* perm  = (const int*)d_in[12];
  const int* esrc = ei;
  const int* edst = ei + EE;

  char* ws = (char*)d_ws;
  size_t off = 0;
  auto alloc = [&](size_t bytes)->void*{ void* p = ws + off; off += (bytes + 255) & ~(size_t)255; return p; };
  unsigned short* z  = (unsigned short*)alloc((size_t)NN*256*2);
  unsigned short* ob = (unsigned short*)alloc((size_t)2*NN*128*2);
  unsigned short* tz = (unsigned short*)alloc((size_t)NN*128*2);
  unsigned short* th = (unsigned short*)alloc((size_t)NN*32*2);
  int* deg = (int*)alloc((size_t)2*NN*4);
  int* dout_ = deg; int* din_ = deg + NN;
  float* ns = (float*)alloc((size_t)NN*4);
  float* nd = (float*)alloc((size_t)NN*4);
  float* rn = (float*)alloc((size_t)2*NN*4);
  int* cursor = (int*)alloc((size_t)NN*4);
  int* row_ptr = (int*)alloc((size_t)(NN+1)*4);
  int2* colx2 = (int2*)alloc((size_t)EE*8);
  int* chunk = (int*)alloc((size_t)NN*4);
  int* bsum = (int*)alloc((size_t)SCB*4);
  unsigned short* W1T = (unsigned short*)alloc((size_t)1024*128*2);
  unsigned short* W2T = (unsigned short*)alloc((size_t)128*128*2);
  unsigned short* WdoB = (unsigned short*)alloc((size_t)128*128*2);
  unsigned short* W3c = (unsigned short*)alloc((size_t)16*128*2);

  float* out_h   = (float*)d_out;
  float* out_ro  = out_h  + (size_t)NN*16;
  float* out_rh  = out_ro + (size_t)NN*2;
  float* out_roa = out_rh + (size_t)NN*2;
  float* out_rha = out_roa+ (size_t)NN*2;

  // W1 convert + deg zeroing (replaces memset + part of wcvt)
  k_wcvt_mem<<<708, 256, 0, stream>>>(W1, W1T, deg);
  // GC1 GEMM half 1 + degree counting + small weight conversions, overlapped
  k_g1<0><<<NG1 + FB + WXB, 512, 0, stream>>>(x, W1T, tz, esrc, edst, dout_, din_,
                                        nullptr, perm, 0, W2T, WdoB, W3c, W2, Wdo, W3);
  k_scan1<<<SCB, 1024, 0, stream>>>(din_, chunk, bsum);
  k_scan3b<<<(NN+255)/256, 256, 0, stream>>>(din_, chunk, bsum, dout_, row_ptr, cursor, ns, nd);
  // GC1 GEMM half 2 + CSR fill, overlapped
  k_g1<1><<<NG1 + FB, 512, 0, stream>>>(x, W1T, tz, esrc, edst, cursor, nullptr,
                                        colx2, perm, NG1, nullptr, nullptr, nullptr,
                                        nullptr, nullptr, nullptr);

  int gb2 = (2*NN)/64;
  // GC1 aggregation: both encodes via folded perm-gather from t
  k_agg1<<<(NN+3)/4,256,0,stream>>>(tz, ns, row_ptr, colx2, nd, b1, ob);
  // GC2 fused over both encodes, +residual agg (fuses rn)
  k_gemmA<128,0,1><<<gb2,256,0,stream>>>(ob, W2T, z, ns, nullptr, 2*NN,
                                         nullptr, nullptr, nullptr, nullptr, nullptr);
  k_agg128<<<(NN+3)/4,256,0,stream>>>(z, row_ptr, colx2, nd, b2, ob, rn);
  // disc GEMM + fused GC3-mult (th) + fused ret_o epilogue
  k_gemmA<128,1,3><<<gb2,256,0,stream>>>(ob, WdoB, nullptr, bdo, rn, 2*NN,
                                         out_ro, out_roa, W3c, ns, th);
  // GC3 agg + fused ret_h
  k_agg16<<<(NN+3)/4,256,0,stream>>>(th, row_ptr, colx2, nd, b3, Wdh, bdh, out_h, out_rh, out_rha);
}